// Round 7
// baseline (991.453 us; speedup 1.0000x reference)
//
#include <hip/hip_runtime.h>

// ---------------------------------------------------------------------------
// HierarchicalBiLSTM_CRF on MI355X (gfx950) — round 15
//
// Round-15: j-split the recurrence across 2 CUs per group.
// r10/r11/r14 all compiled to the same 11.5k cyc/step code (VGPR 128,
// SGPR 112): per-CU weight stream 384KB/step through a 64B/cyc L1 is the
// structural floor of the 1-block-per-group partition. New partition:
// 2 blocks per group, each owning 128 of the 256 h-dims (512 gate cols).
//   own-h weight sections (kt in [half*4, half*4+4)) -> ALL in LDS (128KB)
//   partner sections -> streamed 128KB/step (floor ~2k cyc, was 6k)
// Per-step 4KB h-half exchange via global memory:
//   producer: epilogue stores h(t) to xh slot (t&1); top of step t+1:
//   __syncthreads (drains stores) then tid0 release-store cnt=t+1.
//   consumer: poll acquire cnt>=t, then read partner A-frags DIRECTLY from
//   xh slot ((t-1)&1) as MFMA A operands (no LDS staging, no 2nd barrier).
// Back-pressure: my epilogue(t+2) overwrites slot t&1 only after my poll
// saw partner cnt>=t+2, i.e. partner finished its step t+1 read. Partners
// share a group -> same step count -> no deadlock; 128 blocks at 1/CU are
// co-resident; pairs are blockIdx b and b^8 -> same XCD L2.
// ---------------------------------------------------------------------------

typedef __attribute__((ext_vector_type(8))) short s16x8;
typedef __attribute__((ext_vector_type(4))) float f32x4;
typedef __attribute__((ext_vector_type(2))) unsigned int u32x2;
typedef __attribute__((ext_vector_type(4))) unsigned int u32x4;

__device__ __forceinline__ unsigned short f2bf(float f) {
  unsigned u = __builtin_bit_cast(unsigned, f);
  u += 0x7fff + ((u >> 16) & 1);   // RNE
  return (unsigned short)(u >> 16);
}
__device__ __forceinline__ float bf2f(unsigned short h) {
  unsigned u = ((unsigned)h) << 16;
  return __builtin_bit_cast(float, u);
}
__device__ __forceinline__ float sigm(float x) { return 1.f / (1.f + __expf(-x)); }
__device__ __forceinline__ float tanh_(float x) { return 1.f - 2.f / (__expf(2.f * x) + 1.f); }

union PK8 { s16x8 v; unsigned short u[8]; };

// ---------------------------------------------------------------------------
// K0a: cast input-projection weights to bf16 (pad K 300->320 for token Wih)
__global__ void prep_weights(const float* __restrict__ wihf, const float* __restrict__ wihb,
                             const float* __restrict__ wcf, const float* __restrict__ wcb,
                             unsigned short* __restrict__ o_wf, unsigned short* __restrict__ o_wb,
                             unsigned short* __restrict__ o_wcf, unsigned short* __restrict__ o_wcb) {
  const int job = blockIdx.y, r = blockIdx.x, tid = threadIdx.x;
  const float* src; unsigned short* dst; int Ks, Kd;
  switch (job) {
    case 0: src = wihf; dst = o_wf;   Ks = 300; Kd = 320; break;
    case 1: src = wihb; dst = o_wb;   Ks = 300; Kd = 320; break;
    case 2: src = wcf;  dst = o_wcf;  Ks = 512; Kd = 512; break;
    default:src = wcb;  dst = o_wcb;  Ks = 512; Kd = 512; break;
  }
  for (int c = tid; c < Kd; c += 256)
    dst[r * Kd + c] = f2bf(c < Ks ? src[r * Ks + c] : 0.f);
}

// ---------------------------------------------------------------------------
// K0c: repack recurrent weights [1024][256] f32 -> fragment-major bf16.
// fid = (jt*8 + kt)*4 + g  (jt = j-tile 0..15, kt = k-section 0..7, g = gate)
__global__ __launch_bounds__(256)
void prep_whh_frag(const float* __restrict__ w0, const float* __restrict__ w1,
                   const float* __restrict__ w2,
                   unsigned short* __restrict__ o0, unsigned short* __restrict__ o1,
                   unsigned short* __restrict__ o2) {
  const float* src = blockIdx.y == 0 ? w0 : (blockIdx.y == 1 ? w1 : w2);
  unsigned short* dst = blockIdx.y == 0 ? o0 : (blockIdx.y == 1 ? o1 : o2);
  const int fid = blockIdx.x;
  const int g = fid & 3, kt = (fid >> 2) & 7, jt = fid >> 5;
  for (int i = threadIdx.x; i < 512; i += 256) {
    const int lane = i >> 3, e = i & 7;
    const int cc = lane & 15, qq = lane >> 4;
    const int row = g * 256 + jt * 16 + cc;
    const int col = kt * 32 + qq * 8 + e;
    dst[(size_t)fid * 512 + i] = f2bf(src[row * 256 + col]);
  }
}

// ---------------------------------------------------------------------------
__global__ void prep_small(const int* __restrict__ x, const int* __restrict__ xcl,
                           int* __restrict__ clens, int* __restrict__ lastv,
                           int* __restrict__ order, int* __restrict__ glen) {
  __shared__ int start[65];
  const int n = threadIdx.x;  // 1024 threads
  if (n < 65) start[n] = 0;
  __syncthreads();
  int len = xcl[n]; len = len < 1 ? 1 : (len > 64 ? 64 : len);
  clens[n] = len;
  lastv[n] = x[n * 64 + len - 1];
  atomicAdd(&start[len], 1);
  __syncthreads();
  if (n == 0) {
    int acc = 0;
    for (int l = 64; l >= 1; --l) { int h = start[l]; start[l] = acc; acc += h; }
  }
  __syncthreads();
  int pos = atomicAdd(&start[len], 1);
  order[pos] = n;
  __syncthreads();
  if (n < 64) glen[n] = clens[order[n * 16]];   // descending -> 16-group max
}

// ---------------------------------------------------------------------------
// Unified GEMM: C[M][1024](bf16) = A(rows via rowmap)[M][Klog](f32) x B[1024][KP](bf16)^T
__global__ __launch_bounds__(256, 2)
void gemm_bf(const float* __restrict__ A, const int* __restrict__ rowmap,
             int Mrows, int Astride, int Klog, int KP,
             const unsigned short* __restrict__ B, unsigned short* __restrict__ C) {
  __shared__ unsigned short As[128 * 40];
  __shared__ unsigned short Ep[4][64 * 136];
  const int tid = threadIdx.x;
  const int lane = tid & 63, w = tid >> 6;
  const int wrow = w >> 1, wcol = w & 1;
  const int cc = lane & 15, qq = lane >> 4;
  const int m0 = blockIdx.y * 128, n0 = blockIdx.x * 256;

  f32x4 zz = {0.f, 0.f, 0.f, 0.f};
  f32x4 acc[4][8];
#pragma unroll
  for (int i = 0; i < 4; ++i)
#pragma unroll
    for (int j = 0; j < 8; ++j) acc[i][j] = zz;

  const int arow = tid >> 1, ahalf = tid & 1;
  const float* arp = nullptr;
  {
    int av = m0 + arow;
    if (av < Mrows) {
      int amap = rowmap ? rowmap[av] : av;
      arp = A + (long)amap * Astride;
    }
  }

  const int nktiles = KP >> 5;
  for (int kt = 0; kt < nktiles; ++kt) {
    const int k0 = kt << 5;
    __syncthreads();
    {
      const int kb = k0 + ahalf * 16;
      unsigned short hv[16];
      if (arp && kb + 16 <= Klog) {
        const float* p = arp + kb;
#pragma unroll
        for (int i = 0; i < 16; i += 4) {
          f32x4 t = *(const f32x4*)(p + i);
          hv[i] = f2bf(t.x); hv[i + 1] = f2bf(t.y);
          hv[i + 2] = f2bf(t.z); hv[i + 3] = f2bf(t.w);
        }
      } else {
#pragma unroll
        for (int i = 0; i < 16; ++i) {
          float v = (arp && (kb + i) < Klog) ? arp[kb + i] : 0.f;
          hv[i] = f2bf(v);
        }
      }
      PK8 p0, p1;
#pragma unroll
      for (int i = 0; i < 8; ++i) { p0.u[i] = hv[i]; p1.u[i] = hv[8 + i]; }
      *(s16x8*)&As[arow * 40 + ahalf * 16] = p0.v;
      *(s16x8*)&As[arow * 40 + ahalf * 16 + 8] = p1.v;
    }
    __syncthreads();
    s16x8 af[4];
#pragma unroll
    for (int mt = 0; mt < 4; ++mt)
      af[mt] = *(const s16x8*)&As[(wrow * 64 + mt * 16 + cc) * 40 + qq * 8];
#pragma unroll
    for (int nt = 0; nt < 8; ++nt) {
      const unsigned short* bp = B + (long)(n0 + wcol * 128 + nt * 16 + cc) * KP + k0 + qq * 8;
      s16x8 bfr = *(const s16x8*)bp;
#pragma unroll
      for (int mt = 0; mt < 4; ++mt)
        acc[mt][nt] = __builtin_amdgcn_mfma_f32_16x16x32_bf16(af[mt], bfr, acc[mt][nt], 0, 0, 0);
    }
  }
  __syncthreads();
#pragma unroll
  for (int mt = 0; mt < 4; ++mt)
#pragma unroll
    for (int nt = 0; nt < 8; ++nt)
#pragma unroll
      for (int r = 0; r < 4; ++r)
        Ep[w][(mt * 16 + qq * 4 + r) * 136 + nt * 16 + cc] = f2bf(acc[mt][nt][r]);
  __syncthreads();
#pragma unroll
  for (int it = 0; it < 16; ++it) {
    int row = it * 4 + qq;
    s16x8 d = *(const s16x8*)&Ep[w][row * 136 + cc * 8];
    int gm = m0 + wrow * 64 + row;
    int gn = n0 + wcol * 128 + cc * 8;
    if (gm < Mrows) *(s16x8*)&C[(long)gm * 1024 + gn] = d;
  }
}

// ---------------------------------------------------------------------------
__global__ void bwd_step(const unsigned short* __restrict__ gxb,
                         const float* __restrict__ bias,
                         float* __restrict__ chunks) {
  const int n = blockIdx.x, j = threadIdx.x;  // 1024 x 256
  const unsigned short* row = gxb + (long)n * 1024;
  float gi = bf2f(row[j]) + bias[j];
  float gg = bf2f(row[512 + j]) + bias[512 + j];
  float go = bf2f(row[768 + j]) + bias[768 + j];
  float cn = sigm(gi) * tanh_(gg);
  chunks[(long)n * 512 + 256 + j] = sigm(go) * tanh_(cn);
}

// ---------------------------------------------------------------------------
// K4: pre-gather gate projections (gate-packed j*4+g, bias folded), sorted
// order, T-MAJOR per 16-group: gx[g16][t][m16][j*4+g]. Pad steps unwritten.
__global__ __launch_bounds__(256)
void gather_gx(const unsigned short* __restrict__ proj, const int* __restrict__ x,
               const int* __restrict__ order, const int* __restrict__ clens,
               const int* __restrict__ glen, const float* __restrict__ bias,
               unsigned short* __restrict__ gx) {
  const int t = blockIdx.x, p = blockIdx.y, j = threadIdx.x;
  if (t >= glen[p >> 4]) return;
  const int seq = order[p];
  const int len = clens[seq];
  if (t >= len) return;
  unsigned short* dst = gx + (((size_t)(p >> 4) * 64 + t) * 16 + (p & 15)) * 1024 + j * 4;
  const int tok = x[seq * 64 + t];
  const unsigned short* src = proj + (size_t)tok * 1024 + j;
  unsigned v0 = f2bf(bf2f(src[0]) + bias[j]);
  unsigned v1 = f2bf(bf2f(src[256]) + bias[256 + j]);
  unsigned v2 = f2bf(bf2f(src[512]) + bias[512 + j]);
  unsigned v3 = f2bf(bf2f(src[768]) + bias[768 + j]);
  u32x2 pk = {v0 | (v1 << 16), v2 | (v3 << 16)};
  *(u32x2*)dst = pk;
}

// ---------------------------------------------------------------------------
// K6b: gate-pack gxc with bias folded, T-MAJOR per 16-group, j*4+g layout.
__global__ __launch_bounds__(256)
void repack4(const unsigned short* __restrict__ s0, const unsigned short* __restrict__ s1,
             const float* __restrict__ b0, const float* __restrict__ b1,
             unsigned short* __restrict__ d0, unsigned short* __restrict__ d1) {
  const int r = blockIdx.x, j = threadIdx.x;
  const int m = r >> 5, t = r & 31;
  const int mg = m >> 4, m16 = m & 15;
  const unsigned short* s = (blockIdx.y ? s1 : s0) + (size_t)r * 1024;
  const float* bb = blockIdx.y ? b1 : b0;
  unsigned short* d = (blockIdx.y ? d1 : d0) +
                      (size_t)((mg * 32 + t) * 16 + m16) * 1024 + j * 4;
  unsigned v0 = f2bf(bf2f(s[j]) + bb[j]);
  unsigned v1 = f2bf(bf2f(s[256 + j]) + bb[256 + j]);
  unsigned v2 = f2bf(bf2f(s[512 + j]) + bb[512 + j]);
  unsigned v3 = f2bf(bf2f(s[768 + j]) + bb[768 + j]);
  u32x2 pk = {v0 | (v1 << 16), v2 | (v3 << 16)};
  *(u32x2*)d = pk;
}

// ---------------------------------------------------------------------------
// K5: forward token LSTM, j-split. 128 blocks (64 groups x 2 halves,
// partner = blockIdx ^ 8, same XCD) x 512 threads (8 waves x 16 cols).
// Own-h sections in LDS; partner sections streamed; partner h(t-1) read
// directly from xh after acquire-poll.
__global__ __launch_bounds__(512)
void tok_fwd(const unsigned short* __restrict__ gx,     // [64][64][16][1024]
             const unsigned short* __restrict__ WhP,    // frag-major (jt,kt,g)
             const int* __restrict__ order,
             const int* __restrict__ clens,
             const int* __restrict__ glen,
             unsigned short* __restrict__ xh,           // [64*2][2 slot][16][128]
             unsigned int* __restrict__ cnt,            // [128]
             float* __restrict__ chunks) {
  extern __shared__ unsigned short smem[];
  unsigned short* hbuf = smem;                 // 2 x [16][136] = 4352 shorts
  unsigned short* ldsW = smem + 4352;          // 8 waves * 8192 shorts = 128 KB
  int* sg = (int*)(smem + 4352 + 65536);       // [16]
  int* slen = sg + 16;                         // [16]

  const int tid = threadIdx.x;
  const int lane = tid & 63, w = tid >> 6;     // w in 0..7
  const int cc = lane & 15, qq = lane >> 4;
  const int b = blockIdx.x;
  const int g = (b & 7) | ((b >> 4) << 3);     // group 0..63
  const int half = (b >> 3) & 1;               // j-half

  if (tid < 16) {
    int s = order[g * 16 + tid];
    sg[tid] = s;
    slen[tid] = clens[s];
  }
  for (int i = tid; i < 4352; i += 512) hbuf[i] = 0;

  const int jt = half * 8 + w;                 // j-tile 0..15
  const unsigned short* wOwn = WhP + ((size_t)(jt * 8 + half * 4) * 4) * 512 + lane * 8;
  const unsigned short* wPar = WhP + ((size_t)(jt * 8 + (1 - half) * 4) * 4) * 512 + lane * 8;
  {
    unsigned short* ld = ldsW + w * 8192 + lane * 8;
#pragma unroll
    for (int s = 0; s < 16; ++s)
      *(s16x8*)&ld[s * 512] = *(const s16x8*)&wOwn[s * 512];
  }
  __syncthreads();

  const int maxlen = glen[g];
  int lenr[4];
#pragma unroll
  for (int r = 0; r < 4; ++r) lenr[r] = slen[qq * 4 + r];

  float cst[4];
  unsigned short hreg[4];
#pragma unroll
  for (int i = 0; i < 4; ++i) { cst[i] = 0.f; hreg[i] = 0; }

  const int jl = w * 16 + cc;                  // local col 0..127
  const unsigned short* gx0 = gx + (size_t)g * 64 * 16 * 1024 + (half * 128 + jl) * 4;
  const unsigned short* ldw = ldsW + w * 8192 + lane * 8;
  unsigned int* cme = cnt + b;
  unsigned int* cpp = cnt + (b ^ 8);
  unsigned short* xh_me = xh + (size_t)(g * 2 + half) * 2 * 2048;
  const unsigned short* xh_p = xh + (size_t)(g * 2 + (1 - half)) * 2 * 2048;
  f32x4 zz = {0.f, 0.f, 0.f, 0.f};

  for (int t = 0; t < maxlen; ++t) {
    const unsigned short* hr = hbuf + (t & 1) * 2176;
    unsigned short* hw = hbuf + ((t & 1) ^ 1) * 2176;

    __syncthreads();   // hbuf + xh publish stores of step t-1 drained
    if (t && tid == 0)
      __hip_atomic_store(cme, (unsigned)t, __ATOMIC_RELEASE, __HIP_MEMORY_SCOPE_AGENT);

    // issue partner weight sections 0,1 + gx
    s16x8 S[4], T[4];
    if (t) {
#pragma unroll
      for (int i2 = 0; i2 < 4; ++i2) S[i2] = *(const s16x8*)&wPar[i2 * 512];
    }
    u32x2 gxp[4];
#pragma unroll
    for (int r = 0; r < 4; ++r)
      gxp[r] = *(const u32x2*)(gx0 + ((size_t)t * 16 + qq * 4 + r) * 1024);
    if (t) {
#pragma unroll
      for (int i2 = 0; i2 < 4; ++i2) T[i2] = *(const s16x8*)&wPar[(4 + i2) * 512];
    }

    f32x4 acc[4];
#pragma unroll
    for (int i2 = 0; i2 < 4; ++i2) acc[i2] = zz;

    // own sections (LDS weights, local h)
#pragma unroll
    for (int s = 0; s < 4; ++s) {
      s16x8 a = *(const s16x8*)&hr[cc * 136 + s * 32 + qq * 8];
#pragma unroll
      for (int g4 = 0; g4 < 4; ++g4)
        acc[g4] = __builtin_amdgcn_mfma_f32_16x16x32_bf16(
            a, *(const s16x8*)&ldw[(s * 4 + g4) * 512], acc[g4], 0, 0, 0);
    }

    // partner sections (streamed weights, h from xh after acquire)
    if (t) {
      while (__hip_atomic_load(cpp, __ATOMIC_ACQUIRE, __HIP_MEMORY_SCOPE_AGENT) < (unsigned)t) {}
      const unsigned short* xp = xh_p + ((t + 1) & 1) * 2048;   // slot (t-1)&1
      s16x8 a0 = *(const s16x8*)(xp + cc * 128 + 0 * 32 + qq * 8);
      s16x8 a1 = *(const s16x8*)(xp + cc * 128 + 1 * 32 + qq * 8);
      s16x8 a2 = *(const s16x8*)(xp + cc * 128 + 2 * 32 + qq * 8);
      s16x8 a3 = *(const s16x8*)(xp + cc * 128 + 3 * 32 + qq * 8);
#pragma unroll
      for (int g4 = 0; g4 < 4; ++g4)
        acc[g4] = __builtin_amdgcn_mfma_f32_16x16x32_bf16(a0, S[g4], acc[g4], 0, 0, 0);
#pragma unroll
      for (int i2 = 0; i2 < 4; ++i2) S[i2] = *(const s16x8*)&wPar[(8 + i2) * 512];
#pragma unroll
      for (int g4 = 0; g4 < 4; ++g4)
        acc[g4] = __builtin_amdgcn_mfma_f32_16x16x32_bf16(a1, T[g4], acc[g4], 0, 0, 0);
#pragma unroll
      for (int i2 = 0; i2 < 4; ++i2) T[i2] = *(const s16x8*)&wPar[(12 + i2) * 512];
#pragma unroll
      for (int g4 = 0; g4 < 4; ++g4)
        acc[g4] = __builtin_amdgcn_mfma_f32_16x16x32_bf16(a2, S[g4], acc[g4], 0, 0, 0);
#pragma unroll
      for (int g4 = 0; g4 < 4; ++g4)
        acc[g4] = __builtin_amdgcn_mfma_f32_16x16x32_bf16(a3, T[g4], acc[g4], 0, 0, 0);
    }

    // epilogue: gates, state update, local h + publish
    unsigned short* xme = xh_me + (t & 1) * 2048;
#pragma unroll
    for (int r = 0; r < 4; ++r) {
      const int m = qq * 4 + r;
      const u32x2 pk = gxp[r];
      float gi = acc[0][r] + bf2f((unsigned short)(pk.x & 0xffff));
      float gf = acc[1][r] + bf2f((unsigned short)(pk.x >> 16));
      float gg = acc[2][r] + bf2f((unsigned short)(pk.y & 0xffff));
      float go = acc[3][r] + bf2f((unsigned short)(pk.y >> 16));
      if (t < lenr[r]) {
        float cn = sigm(gf) * cst[r] + sigm(gi) * tanh_(gg);
        cst[r] = cn;
        hreg[r] = f2bf(sigm(go) * tanh_(cn));
      }
      hw[m * 136 + jl] = hreg[r];     // frozen carry, own half
      xme[m * 128 + jl] = hreg[r];    // publish for partner
    }
  }

#pragma unroll
  for (int r = 0; r < 4; ++r)
    chunks[(size_t)sg[qq * 4 + r] * 512 + half * 128 + jl] = bf2f(hreg[r]);
}

// ---------------------------------------------------------------------------
// K7: chunk BiLSTM, j-split. 8 blocks (dir x mgroup x half, partner b^4)
// x 512 threads. Same exchange structure as tok_fwd (32 steps, keyed by tt).
__global__ __launch_bounds__(512)
void chunk_rec(const unsigned short* __restrict__ gxf,   // [mg][32][16][1024]
               const unsigned short* __restrict__ gxb,
               const unsigned short* __restrict__ WhPf,
               const unsigned short* __restrict__ WhPb,
               const int* __restrict__ xlen,
               unsigned short* __restrict__ xh,          // [8][2][16][128]
               unsigned int* __restrict__ cnt,           // [8]
               unsigned short* __restrict__ ch) {
  extern __shared__ unsigned short smem[];
  unsigned short* hbuf = smem;                 // 2 x 2176 shorts
  unsigned short* ldsW = smem + 4352;          // 65536 shorts

  const int tid = threadIdx.x;
  const int lane = tid & 63, w = tid >> 6;
  const int cc = lane & 15, qq = lane >> 4;
  const int b = blockIdx.x;
  const int dir = b & 1, mg = (b >> 1) & 1, half = (b >> 2) & 1;
  const unsigned short* gx = (dir ? gxb : gxf) + (size_t)mg * 32 * 16 * 1024;
  const unsigned short* WhP = dir ? WhPb : WhPf;

  for (int i = tid; i < 4352; i += 512) hbuf[i] = 0;

  const int jt = half * 8 + w;
  const unsigned short* wOwn = WhP + ((size_t)(jt * 8 + half * 4) * 4) * 512 + lane * 8;
  const unsigned short* wPar = WhP + ((size_t)(jt * 8 + (1 - half) * 4) * 4) * 512 + lane * 8;
  {
    unsigned short* ld = ldsW + w * 8192 + lane * 8;
#pragma unroll
    for (int s = 0; s < 16; ++s)
      *(s16x8*)&ld[s * 512] = *(const s16x8*)&wOwn[s * 512];
  }
  __syncthreads();

  int lenr[4];
#pragma unroll
  for (int r = 0; r < 4; ++r) {
    int L = xlen[mg * 16 + qq * 4 + r];
    lenr[r] = L > 32 ? 32 : L;
  }

  float cst[4];
  unsigned short hreg[4];
#pragma unroll
  for (int i = 0; i < 4; ++i) { cst[i] = 0.f; hreg[i] = 0; }

  const int jl = w * 16 + cc;
  const unsigned short* gxl = gx + (half * 128 + jl) * 4;
  const unsigned short* ldw = ldsW + w * 8192 + lane * 8;
  unsigned int* cme = cnt + b;
  unsigned int* cpp = cnt + (b ^ 4);
  unsigned short* xh_me = xh + (size_t)((b & 3) * 2 + half) * 2 * 2048;
  const unsigned short* xh_p = xh + (size_t)((b & 3) * 2 + (1 - half)) * 2 * 2048;
  f32x4 zz = {0.f, 0.f, 0.f, 0.f};

  for (int tt = 0; tt < 32; ++tt) {
    const int t = dir ? (31 - tt) : tt;
    const unsigned short* hr = hbuf + (tt & 1) * 2176;
    unsigned short* hw = hbuf + ((tt & 1) ^ 1) * 2176;

    __syncthreads();
    if (tt && tid == 0)
      __hip_atomic_store(cme, (unsigned)tt, __ATOMIC_RELEASE, __HIP_MEMORY_SCOPE_AGENT);

    s16x8 S[4], T[4];
    if (tt) {
#pragma unroll
      for (int i2 = 0; i2 < 4; ++i2) S[i2] = *(const s16x8*)&wPar[i2 * 512];
    }
    u32x2 gxp[4];
#pragma unroll
    for (int r = 0; r < 4; ++r)
      gxp[r] = *(const u32x2*)(gxl + ((size_t)t * 16 + qq * 4 + r) * 1024);
    if (tt) {
#pragma unroll
      for (int i2 = 0; i2 < 4; ++i2) T[i2] = *(const s16x8*)&wPar[(4 + i2) * 512];
    }

    f32x4 acc[4];
#pragma unroll
    for (int i2 = 0; i2 < 4; ++i2) acc[i2] = zz;

#pragma unroll
    for (int s = 0; s < 4; ++s) {
      s16x8 a = *(const s16x8*)&hr[cc * 136 + s * 32 + qq * 8];
#pragma unroll
      for (int g4 = 0; g4 < 4; ++g4)
        acc[g4] = __builtin_amdgcn_mfma_f32_16x16x32_bf16(
            a, *(const s16x8*)&ldw[(s * 4 + g4) * 512], acc[g4], 0, 0, 0);
    }

    if (tt) {
      while (__hip_atomic_load(cpp, __ATOMIC_ACQUIRE, __HIP_MEMORY_SCOPE_AGENT) < (unsigned)tt) {}
      const unsigned short* xp = xh_p + ((tt + 1) & 1) * 2048;
      s16x8 a0 = *(const s16x8*)(xp + cc * 128 + 0 * 32 + qq * 8);
      s16x8 a1 = *(const s16x8*)(xp + cc * 128 + 1 * 32 + qq * 8);
      s16x8 a2 = *(const s16x8*)(xp + cc * 128 + 2 * 32 + qq * 8);
      s16x8 a3 = *(const s16x8*)(xp + cc * 128 + 3 * 32 + qq * 8);
#pragma unroll
      for (int g4 = 0; g4 < 4; ++g4)
        acc[g4] = __builtin_amdgcn_mfma_f32_16x16x32_bf16(a0, S[g4], acc[g4], 0, 0, 0);
#pragma unroll
      for (int i2 = 0; i2 < 4; ++i2) S[i2] = *(const s16x8*)&wPar[(8 + i2) * 512];
#pragma unroll
      for (int g4 = 0; g4 < 4; ++g4)
        acc[g4] = __builtin_amdgcn_mfma_f32_16x16x32_bf16(a1, T[g4], acc[g4], 0, 0, 0);
#pragma unroll
      for (int i2 = 0; i2 < 4; ++i2) T[i2] = *(const s16x8*)&wPar[(12 + i2) * 512];
#pragma unroll
      for (int g4 = 0; g4 < 4; ++g4)
        acc[g4] = __builtin_amdgcn_mfma_f32_16x16x32_bf16(a2, S[g4], acc[g4], 0, 0, 0);
#pragma unroll
      for (int g4 = 0; g4 < 4; ++g4)
        acc[g4] = __builtin_amdgcn_mfma_f32_16x16x32_bf16(a3, T[g4], acc[g4], 0, 0, 0);
    }

    unsigned short* xme = xh_me + (tt & 1) * 2048;
#pragma unroll
    for (int r = 0; r < 4; ++r) {
      const int m = qq * 4 + r;
      const u32x2 pk = gxp[r];
      float gi = acc[0][r] + bf2f((unsigned short)(pk.x & 0xffff));
      float gf = acc[1][r] + bf2f((unsigned short)(pk.x >> 16));
      float gg = acc[2][r] + bf2f((unsigned short)(pk.y & 0xffff));
      float go = acc[3][r] + bf2f((unsigned short)(pk.y >> 16));
      unsigned short out16 = 0;
      if (t < lenr[r]) {
        float cn = sigm(gf) * cst[r] + sigm(gi) * tanh_(gg);
        cst[r] = cn;
        hreg[r] = f2bf(sigm(go) * tanh_(cn));
        out16 = hreg[r];
      }
      hw[m * 136 + jl] = hreg[r];
      xme[m * 128 + jl] = hreg[r];
      ch[(size_t)((mg * 16 + m) * 32 + t) * 512 + dir * 256 + half * 128 + jl] = out16;
    }
  }
}

// ---------------------------------------------------------------------------
__global__ __launch_bounds__(64)
void fc_kernel(const unsigned short* __restrict__ ch, const float* __restrict__ W,
               const float* __restrict__ bfc, float* __restrict__ out) {
  const int n = blockIdx.x, lane = threadIdx.x;
  float xv[8];
  const unsigned short* cp = ch + (long)n * 512 + lane * 8;
#pragma unroll
  for (int i = 0; i < 8; ++i) xv[i] = bf2f(cp[i]);
  float s[9];
#pragma unroll
  for (int k = 0; k < 9; ++k) {
    const float* wr = W + k * 512 + lane * 8;
    float t = 0.f;
#pragma unroll
    for (int i = 0; i < 8; ++i) t += xv[i] * wr[i];
    s[k] = t;
  }
#pragma unroll
  for (int off = 32; off; off >>= 1)
#pragma unroll
    for (int k = 0; k < 9; ++k) s[k] += __shfl_down(s[k], off, 64);
  if (lane == 0) {
#pragma unroll
    for (int k = 0; k < 9; ++k) out[n * 9 + k] = s[k] + bfc[k];
  }
}

// ---------------------------------------------------------------------------
extern "C" void kernel_launch(void* const* d_in, const int* in_sizes, int n_in,
                              void* d_out, int out_size, void* d_ws, size_t ws_size,
                              hipStream_t stream) {
  const int*   x           = (const int*)d_in[0];
  const int*   x_len       = (const int*)d_in[2];
  const int*   x_chunk_len = (const int*)d_in[3];
  const float* emb         = (const float*)d_in[4];
  const float* tok_Wih_f   = (const float*)d_in[5];
  const float* tok_Whh_f   = (const float*)d_in[6];
  const float* tok_b_f     = (const float*)d_in[7];
  const float* tok_Wih_b   = (const float*)d_in[8];
  // d_in[9] tok_Whh_b: unused (reverse masked scan at t=clen-1 starts from zero state)
  const float* tok_b_b     = (const float*)d_in[10];
  const float* chk_Wih_f   = (const float*)d_in[11];
  const float* chk_Whh_f   = (const float*)d_in[12];
  const float* chk_b_f     = (const float*)d_in[13];
  const float* chk_Wih_b   = (const float*)d_in[14];
  const float* chk_Whh_b   = (const float*)d_in[15];
  const float* chk_b_b     = (const float*)d_in[16];
  const float* fc_W        = (const float*)d_in[17];
  const float* fc_b        = (const float*)d_in[18];
  float* out = (float*)d_out;

  char* ws = (char*)d_ws;
  size_t off = 0;
  auto alloc = [&](size_t bytes) -> void* {
    void* p = ws + off;
    off += (bytes + 255) & ~(size_t)255;
    return p;
  };
  unsigned short* Wf   = (unsigned short*)alloc((size_t)1024 * 320 * 2);
  unsigned short* Wb   = (unsigned short*)alloc((size_t)1024 * 320 * 2);
  unsigned short* Wcf  = (unsigned short*)alloc((size_t)1024 * 512 * 2);
  unsigned short* Wcb  = (unsigned short*)alloc((size_t)1024 * 512 * 2);
  unsigned short* WhPtok=(unsigned short*)alloc((size_t)512 * 512 * 2);   // frag-major
  unsigned short* WhPcf= (unsigned short*)alloc((size_t)512 * 512 * 2);
  unsigned short* WhPcb= (unsigned short*)alloc((size_t)512 * 512 * 2);
  unsigned short* proj = (unsigned short*)alloc((size_t)30000 * 1024 * 2);
  unsigned short* gxbb = (unsigned short*)alloc((size_t)1024 * 1024 * 2);
  unsigned short* gxcf = (unsigned short*)alloc((size_t)1024 * 1024 * 2);
  unsigned short* gxcb = (unsigned short*)alloc((size_t)1024 * 1024 * 2);
  unsigned short* gxcfp= (unsigned short*)alloc((size_t)1024 * 1024 * 2);
  unsigned short* gxcbp= (unsigned short*)alloc((size_t)1024 * 1024 * 2);
  float*          chunks = (float*)alloc((size_t)1024 * 512 * 4);
  unsigned short* cho  = (unsigned short*)alloc((size_t)1024 * 512 * 2);
  unsigned short* gxs  = (unsigned short*)alloc((size_t)1024 * 64 * 1024 * 2);  // 134 MB
  unsigned short* xhT  = (unsigned short*)alloc((size_t)64 * 2 * 2 * 2048 * 2); // 1 MB
  unsigned short* xhC  = (unsigned short*)alloc((size_t)8 * 2 * 2048 * 2);      // 64 KB
  unsigned int* cntT = (unsigned int*)alloc(128 * 4);
  unsigned int* cntC = (unsigned int*)alloc(8 * 4);
  int* clens = (int*)alloc(1024 * 4);
  int* lastv = (int*)alloc(1024 * 4);
  int* order = (int*)alloc(1024 * 4);
  int* glen  = (int*)alloc(64 * 4);

  // allow >64 KB dynamic LDS for the recurrent kernels (gfx950: 160 KB/CU)
  hipFuncSetAttribute((const void*)tok_fwd,
                      hipFuncAttributeMaxDynamicSharedMemorySize, 139904);
  hipFuncSetAttribute((const void*)chunk_rec,
                      hipFuncAttributeMaxDynamicSharedMemorySize, 139776);

  // zero the exchange counters each launch (graph-capturable)
  hipMemsetAsync(cntT, 0, 128 * 4, stream);
  hipMemsetAsync(cntC, 0, 8 * 4, stream);

  prep_weights<<<dim3(1024, 4), 256, 0, stream>>>(
      tok_Wih_f, tok_Wih_b, chk_Wih_f, chk_Wih_b, Wf, Wb, Wcf, Wcb);
  prep_whh_frag<<<dim3(512, 3), 256, 0, stream>>>(
      tok_Whh_f, chk_Whh_f, chk_Whh_b, WhPtok, WhPcf, WhPcb);
  prep_small<<<1, 1024, 0, stream>>>(x, x_chunk_len, clens, lastv, order, glen);

  // vocab pre-projection: proj = emb x tok_Wih_f^T
  gemm_bf<<<dim3(4, 235), 256, 0, stream>>>(emb, nullptr, 30000, 300, 300, 320, Wf, proj);
  // backward gx for last tokens only
  gemm_bf<<<dim3(4, 8), 256, 0, stream>>>(emb, lastv, 1024, 300, 300, 320, Wb, gxbb);
  bwd_step<<<1024, 256, 0, stream>>>(gxbb, tok_b_b, chunks);
  // pre-gather forward gate projections (gate-packed, bias folded, t-major/16)
  gather_gx<<<dim3(64, 1024), 256, 0, stream>>>(proj, x, order, clens, glen, tok_b_f, gxs);
  // forward token recurrence: 128 blocks (64 groups x 2 j-halves)
  tok_fwd<<<128, 512, 139904, stream>>>(gxs, WhPtok, order, clens, glen, xhT, cntT, chunks);
  // chunk-level input projections
  gemm_bf<<<dim3(4, 8), 256, 0, stream>>>(chunks, nullptr, 1024, 512, 512, 512, Wcf, gxcf);
  gemm_bf<<<dim3(4, 8), 256, 0, stream>>>(chunks, nullptr, 1024, 512, 512, 512, Wcb, gxcb);
  repack4<<<dim3(1024, 2), 256, 0, stream>>>(gxcf, gxcb, chk_b_f, chk_b_b, gxcfp, gxcbp);
  // chunk BiLSTM: 8 blocks (2 dir x 2 m-groups x 2 j-halves)
  chunk_rec<<<8, 512, 139776, stream>>>(gxcfp, gxcbp, WhPcf, WhPcb, x_len, xhC, cntC, cho);
  // final FC
  fc_kernel<<<1024, 64, 0, stream>>>(cho, fc_W, fc_b, out);
}

// Round 8
// 933.438 us; speedup vs baseline: 1.0622x; 1.0622x over previous
//
#include <hip/hip_runtime.h>

// ---------------------------------------------------------------------------
// HierarchicalBiLSTM_CRF on MI355X (gfx950) — round 16
//
// Round-16: 16-wave recurrent blocks so the stream double-buffer FITS in
// registers. r10/r11/r14 (8-wave) all compiled to the same ~11.5k cyc/step
// code: acc[8]+S/T = 96 regs + misc > 128-reg cap -> allocator spilled every
// source-level buffer; 48 frag loads/wave serialized on consume-order vmcnt
// (55% of the 6k-cyc L1-fill floor). r15's cross-CU j-split regressed
// (agent-scope acquire invalidates L1 every step; WRITE_SIZE 3.8->17.9MB).
// New shape: 64 blocks x 1024 thr (16 waves x 16 j-cols, 4 waves/SIMD).
//   kt0-1 -> LDS (16 waves x 8 frags = 128 KB)
//   kt2-7 -> streamed via S[4]/T[4] double-buffer (one section in flight
//            ahead; gx issued between kt2/kt3, retires mid-step)
// Loop working set ~95 VGPRs < 128 cap -> buffers survive allocation, and
// 4 waves/SIMD doubles the TLP hiding L2 latency.
// ---------------------------------------------------------------------------

typedef __attribute__((ext_vector_type(8))) short s16x8;
typedef __attribute__((ext_vector_type(4))) float f32x4;
typedef __attribute__((ext_vector_type(2))) unsigned int u32x2;
typedef __attribute__((ext_vector_type(4))) unsigned int u32x4;

__device__ __forceinline__ unsigned short f2bf(float f) {
  unsigned u = __builtin_bit_cast(unsigned, f);
  u += 0x7fff + ((u >> 16) & 1);   // RNE
  return (unsigned short)(u >> 16);
}
__device__ __forceinline__ float bf2f(unsigned short h) {
  unsigned u = ((unsigned)h) << 16;
  return __builtin_bit_cast(float, u);
}
__device__ __forceinline__ float sigm(float x) { return 1.f / (1.f + __expf(-x)); }
__device__ __forceinline__ float tanh_(float x) { return 1.f - 2.f / (__expf(2.f * x) + 1.f); }

union PK8 { s16x8 v; unsigned short u[8]; };

// ---------------------------------------------------------------------------
// K0a: cast input-projection weights to bf16 (pad K 300->320 for token Wih)
__global__ void prep_weights(const float* __restrict__ wihf, const float* __restrict__ wihb,
                             const float* __restrict__ wcf, const float* __restrict__ wcb,
                             unsigned short* __restrict__ o_wf, unsigned short* __restrict__ o_wb,
                             unsigned short* __restrict__ o_wcf, unsigned short* __restrict__ o_wcb) {
  const int job = blockIdx.y, r = blockIdx.x, tid = threadIdx.x;
  const float* src; unsigned short* dst; int Ks, Kd;
  switch (job) {
    case 0: src = wihf; dst = o_wf;   Ks = 300; Kd = 320; break;
    case 1: src = wihb; dst = o_wb;   Ks = 300; Kd = 320; break;
    case 2: src = wcf;  dst = o_wcf;  Ks = 512; Kd = 512; break;
    default:src = wcb;  dst = o_wcb;  Ks = 512; Kd = 512; break;
  }
  for (int c = tid; c < Kd; c += 256)
    dst[r * Kd + c] = f2bf(c < Ks ? src[r * Ks + c] : 0.f);
}

// ---------------------------------------------------------------------------
// K0c: repack recurrent weights [1024][256] f32 -> fragment-major bf16.
// fid = (jt*8 + kt)*4 + g  (jt = j-tile 0..15, kt = k-section 0..7, g = gate)
__global__ __launch_bounds__(256)
void prep_whh_frag(const float* __restrict__ w0, const float* __restrict__ w1,
                   const float* __restrict__ w2,
                   unsigned short* __restrict__ o0, unsigned short* __restrict__ o1,
                   unsigned short* __restrict__ o2) {
  const float* src = blockIdx.y == 0 ? w0 : (blockIdx.y == 1 ? w1 : w2);
  unsigned short* dst = blockIdx.y == 0 ? o0 : (blockIdx.y == 1 ? o1 : o2);
  const int fid = blockIdx.x;
  const int g = fid & 3, kt = (fid >> 2) & 7, jt = fid >> 5;
  for (int i = threadIdx.x; i < 512; i += 256) {
    const int lane = i >> 3, e = i & 7;
    const int cc = lane & 15, qq = lane >> 4;
    const int row = g * 256 + jt * 16 + cc;
    const int col = kt * 32 + qq * 8 + e;
    dst[(size_t)fid * 512 + i] = f2bf(src[row * 256 + col]);
  }
}

// ---------------------------------------------------------------------------
__global__ void prep_small(const int* __restrict__ x, const int* __restrict__ xcl,
                           int* __restrict__ clens, int* __restrict__ lastv,
                           int* __restrict__ order, int* __restrict__ glen) {
  __shared__ int start[65];
  const int n = threadIdx.x;  // 1024 threads
  if (n < 65) start[n] = 0;
  __syncthreads();
  int len = xcl[n]; len = len < 1 ? 1 : (len > 64 ? 64 : len);
  clens[n] = len;
  lastv[n] = x[n * 64 + len - 1];
  atomicAdd(&start[len], 1);
  __syncthreads();
  if (n == 0) {
    int acc = 0;
    for (int l = 64; l >= 1; --l) { int h = start[l]; start[l] = acc; acc += h; }
  }
  __syncthreads();
  int pos = atomicAdd(&start[len], 1);
  order[pos] = n;
  __syncthreads();
  if (n < 64) glen[n] = clens[order[n * 16]];   // descending -> 16-group max
}

// ---------------------------------------------------------------------------
// Unified GEMM: C[M][1024](bf16) = A(rows via rowmap)[M][Klog](f32) x B[1024][KP](bf16)^T
__global__ __launch_bounds__(256, 2)
void gemm_bf(const float* __restrict__ A, const int* __restrict__ rowmap,
             int Mrows, int Astride, int Klog, int KP,
             const unsigned short* __restrict__ B, unsigned short* __restrict__ C) {
  __shared__ unsigned short As[128 * 40];
  __shared__ unsigned short Ep[4][64 * 136];
  const int tid = threadIdx.x;
  const int lane = tid & 63, w = tid >> 6;
  const int wrow = w >> 1, wcol = w & 1;
  const int cc = lane & 15, qq = lane >> 4;
  const int m0 = blockIdx.y * 128, n0 = blockIdx.x * 256;

  f32x4 zz = {0.f, 0.f, 0.f, 0.f};
  f32x4 acc[4][8];
#pragma unroll
  for (int i = 0; i < 4; ++i)
#pragma unroll
    for (int j = 0; j < 8; ++j) acc[i][j] = zz;

  const int arow = tid >> 1, ahalf = tid & 1;
  const float* arp = nullptr;
  {
    int av = m0 + arow;
    if (av < Mrows) {
      int amap = rowmap ? rowmap[av] : av;
      arp = A + (long)amap * Astride;
    }
  }

  const int nktiles = KP >> 5;
  for (int kt = 0; kt < nktiles; ++kt) {
    const int k0 = kt << 5;
    __syncthreads();
    {
      const int kb = k0 + ahalf * 16;
      unsigned short hv[16];
      if (arp && kb + 16 <= Klog) {
        const float* p = arp + kb;
#pragma unroll
        for (int i = 0; i < 16; i += 4) {
          f32x4 t = *(const f32x4*)(p + i);
          hv[i] = f2bf(t.x); hv[i + 1] = f2bf(t.y);
          hv[i + 2] = f2bf(t.z); hv[i + 3] = f2bf(t.w);
        }
      } else {
#pragma unroll
        for (int i = 0; i < 16; ++i) {
          float v = (arp && (kb + i) < Klog) ? arp[kb + i] : 0.f;
          hv[i] = f2bf(v);
        }
      }
      PK8 p0, p1;
#pragma unroll
      for (int i = 0; i < 8; ++i) { p0.u[i] = hv[i]; p1.u[i] = hv[8 + i]; }
      *(s16x8*)&As[arow * 40 + ahalf * 16] = p0.v;
      *(s16x8*)&As[arow * 40 + ahalf * 16 + 8] = p1.v;
    }
    __syncthreads();
    s16x8 af[4];
#pragma unroll
    for (int mt = 0; mt < 4; ++mt)
      af[mt] = *(const s16x8*)&As[(wrow * 64 + mt * 16 + cc) * 40 + qq * 8];
#pragma unroll
    for (int nt = 0; nt < 8; ++nt) {
      const unsigned short* bp = B + (long)(n0 + wcol * 128 + nt * 16 + cc) * KP + k0 + qq * 8;
      s16x8 bfr = *(const s16x8*)bp;
#pragma unroll
      for (int mt = 0; mt < 4; ++mt)
        acc[mt][nt] = __builtin_amdgcn_mfma_f32_16x16x32_bf16(af[mt], bfr, acc[mt][nt], 0, 0, 0);
    }
  }
  __syncthreads();
#pragma unroll
  for (int mt = 0; mt < 4; ++mt)
#pragma unroll
    for (int nt = 0; nt < 8; ++nt)
#pragma unroll
      for (int r = 0; r < 4; ++r)
        Ep[w][(mt * 16 + qq * 4 + r) * 136 + nt * 16 + cc] = f2bf(acc[mt][nt][r]);
  __syncthreads();
#pragma unroll
  for (int it = 0; it < 16; ++it) {
    int row = it * 4 + qq;
    s16x8 d = *(const s16x8*)&Ep[w][row * 136 + cc * 8];
    int gm = m0 + wrow * 64 + row;
    int gn = n0 + wcol * 128 + cc * 8;
    if (gm < Mrows) *(s16x8*)&C[(long)gm * 1024 + gn] = d;
  }
}

// ---------------------------------------------------------------------------
__global__ void bwd_step(const unsigned short* __restrict__ gxb,
                         const float* __restrict__ bias,
                         float* __restrict__ chunks) {
  const int n = blockIdx.x, j = threadIdx.x;  // 1024 x 256
  const unsigned short* row = gxb + (long)n * 1024;
  float gi = bf2f(row[j]) + bias[j];
  float gg = bf2f(row[512 + j]) + bias[512 + j];
  float go = bf2f(row[768 + j]) + bias[768 + j];
  float cn = sigm(gi) * tanh_(gg);
  chunks[(long)n * 512 + 256 + j] = sigm(go) * tanh_(cn);
}

// ---------------------------------------------------------------------------
// K4: pre-gather gate projections (gate-packed j*4+g, bias folded), sorted
// order, T-MAJOR per 16-group: gx[g16][t][m16][j*4+g]. Pad steps unwritten.
__global__ __launch_bounds__(256)
void gather_gx(const unsigned short* __restrict__ proj, const int* __restrict__ x,
               const int* __restrict__ order, const int* __restrict__ clens,
               const int* __restrict__ glen, const float* __restrict__ bias,
               unsigned short* __restrict__ gx) {
  const int t = blockIdx.x, p = blockIdx.y, j = threadIdx.x;
  if (t >= glen[p >> 4]) return;
  const int seq = order[p];
  const int len = clens[seq];
  if (t >= len) return;
  unsigned short* dst = gx + (((size_t)(p >> 4) * 64 + t) * 16 + (p & 15)) * 1024 + j * 4;
  const int tok = x[seq * 64 + t];
  const unsigned short* src = proj + (size_t)tok * 1024 + j;
  unsigned v0 = f2bf(bf2f(src[0]) + bias[j]);
  unsigned v1 = f2bf(bf2f(src[256]) + bias[256 + j]);
  unsigned v2 = f2bf(bf2f(src[512]) + bias[512 + j]);
  unsigned v3 = f2bf(bf2f(src[768]) + bias[768 + j]);
  u32x2 pk = {v0 | (v1 << 16), v2 | (v3 << 16)};
  *(u32x2*)dst = pk;
}

// ---------------------------------------------------------------------------
// K6b: gate-pack gxc with bias folded, T-MAJOR per 16-group, j*4+g layout.
__global__ __launch_bounds__(256)
void repack4(const unsigned short* __restrict__ s0, const unsigned short* __restrict__ s1,
             const float* __restrict__ b0, const float* __restrict__ b1,
             unsigned short* __restrict__ d0, unsigned short* __restrict__ d1) {
  const int r = blockIdx.x, j = threadIdx.x;
  const int m = r >> 5, t = r & 31;
  const int mg = m >> 4, m16 = m & 15;
  const unsigned short* s = (blockIdx.y ? s1 : s0) + (size_t)r * 1024;
  const float* bb = blockIdx.y ? b1 : b0;
  unsigned short* d = (blockIdx.y ? d1 : d0) +
                      (size_t)((mg * 32 + t) * 16 + m16) * 1024 + j * 4;
  unsigned v0 = f2bf(bf2f(s[j]) + bb[j]);
  unsigned v1 = f2bf(bf2f(s[256 + j]) + bb[256 + j]);
  unsigned v2 = f2bf(bf2f(s[512 + j]) + bb[512 + j]);
  unsigned v3 = f2bf(bf2f(s[768 + j]) + bb[768 + j]);
  u32x2 pk = {v0 | (v1 << 16), v2 | (v3 << 16)};
  *(u32x2*)d = pk;
}

// ---------------------------------------------------------------------------
// K5: forward token LSTM. 64 blocks x 16 seqs x 1024 threads (16 waves x
// 16 j-cols, 4 waves/SIMD). kt0-1 LDS; kt2-7 streamed S[4]/T[4] double-buf
// (fits the 128-reg cap, unlike the 8-wave variant); gx between kt2/kt3.
__global__ __launch_bounds__(1024, 4)
void tok_fwd(const unsigned short* __restrict__ gx,     // [g16][64][16][1024]
             const unsigned short* __restrict__ WhP,    // frag-major (jt,kt,g)
             const int* __restrict__ order,
             const int* __restrict__ clens,
             const int* __restrict__ glen,
             float* __restrict__ chunks) {
  extern __shared__ unsigned short smem[];
  unsigned short* hbuf = smem;                // 2 x [16][264] = 8448 shorts
  unsigned short* ldsW = smem + 8448;         // 16 waves * 4096 shorts = 128 KB
  int* sg = (int*)(smem + 8448 + 65536);      // [16]
  int* slen = sg + 16;                        // [16]

  const int tid = threadIdx.x;
  const int lane = tid & 63, w = tid >> 6;    // w in 0..15
  const int cc = lane & 15, qq = lane >> 4;
  const int gb = blockIdx.x;

  if (tid < 16) {
    int s = order[gb * 16 + tid];
    sg[tid] = s;
    slen[tid] = clens[s];
  }
  for (int i = tid; i < 8448; i += 1024) hbuf[i] = 0;   // zero t=0 read buffer

  // wave w (j-tile jt=w): frag (kt,g) at ((w*8+kt)*4+g)*512
  const unsigned short* wgl = WhP + ((size_t)w * 8 * 4) * 512 + lane * 8;
  {
    unsigned short* ld = ldsW + w * 4096 + lane * 8;
#pragma unroll
    for (int s = 0; s < 8; ++s)              // kt0-1 x 4 gates
      *(s16x8*)&ld[s * 512] = *(const s16x8*)&wgl[s * 512];
  }
  __syncthreads();

  const int maxlen = glen[gb];
  int lenr[4];
#pragma unroll
  for (int r = 0; r < 4; ++r) lenr[r] = slen[qq * 4 + r];

  float cst[4];
  unsigned short hreg[4];
#pragma unroll
  for (int i = 0; i < 4; ++i) { cst[i] = 0.f; hreg[i] = 0; }

  const int j = w * 16 + cc;
  const unsigned short* gx0 = gx + (size_t)gb * 64 * 16 * 1024 + j * 4;
  const unsigned short* ldw = ldsW + w * 4096 + lane * 8;
  f32x4 zz = {0.f, 0.f, 0.f, 0.f};

  for (int t = 0; t < maxlen; ++t) {
    const unsigned short* hr = hbuf + (t & 1) * 4224;        // read h(t-1)
    unsigned short* hw = hbuf + ((t & 1) ^ 1) * 4224;        // write h(t)

    __syncthreads();   // prev-step hw writes visible

    // issue: S<-kt2 (oldest), gx, T<-kt3 — one section always in flight.
    s16x8 S[4], T[4];
#pragma unroll
    for (int g4 = 0; g4 < 4; ++g4)
      S[g4] = *(const s16x8*)&wgl[(8 + g4) * 512];
    u32x2 gxp[4];
#pragma unroll
    for (int r = 0; r < 4; ++r)
      gxp[r] = *(const u32x2*)(gx0 + ((size_t)t * 16 + qq * 4 + r) * 1024);
#pragma unroll
    for (int g4 = 0; g4 < 4; ++g4)
      T[g4] = *(const s16x8*)&wgl[(12 + g4) * 512];

    f32x4 acc[4];
#pragma unroll
    for (int g4 = 0; g4 < 4; ++g4) acc[g4] = zz;

    // kt0-1 from LDS (covers S/T flight time)
#pragma unroll
    for (int kt = 0; kt < 2; ++kt) {
      s16x8 a = *(const s16x8*)&hr[cc * 264 + kt * 32 + qq * 8];
#pragma unroll
      for (int g4 = 0; g4 < 4; ++g4)
        acc[g4] = __builtin_amdgcn_mfma_f32_16x16x32_bf16(
            a, *(const s16x8*)&ldw[(kt * 4 + g4) * 512], acc[g4], 0, 0, 0);
    }
    // kt2 (S) -> refill S<-kt4
    {
      s16x8 a = *(const s16x8*)&hr[cc * 264 + 2 * 32 + qq * 8];
#pragma unroll
      for (int g4 = 0; g4 < 4; ++g4)
        acc[g4] = __builtin_amdgcn_mfma_f32_16x16x32_bf16(a, S[g4], acc[g4], 0, 0, 0);
    }
#pragma unroll
    for (int g4 = 0; g4 < 4; ++g4)
      S[g4] = *(const s16x8*)&wgl[(16 + g4) * 512];
    // kt3 (T) -> refill T<-kt5
    {
      s16x8 a = *(const s16x8*)&hr[cc * 264 + 3 * 32 + qq * 8];
#pragma unroll
      for (int g4 = 0; g4 < 4; ++g4)
        acc[g4] = __builtin_amdgcn_mfma_f32_16x16x32_bf16(a, T[g4], acc[g4], 0, 0, 0);
    }
#pragma unroll
    for (int g4 = 0; g4 < 4; ++g4)
      T[g4] = *(const s16x8*)&wgl[(20 + g4) * 512];
    // kt4 (S) -> refill S<-kt6
    {
      s16x8 a = *(const s16x8*)&hr[cc * 264 + 4 * 32 + qq * 8];
#pragma unroll
      for (int g4 = 0; g4 < 4; ++g4)
        acc[g4] = __builtin_amdgcn_mfma_f32_16x16x32_bf16(a, S[g4], acc[g4], 0, 0, 0);
    }
#pragma unroll
    for (int g4 = 0; g4 < 4; ++g4)
      S[g4] = *(const s16x8*)&wgl[(24 + g4) * 512];
    // kt5 (T) -> refill T<-kt7
    {
      s16x8 a = *(const s16x8*)&hr[cc * 264 + 5 * 32 + qq * 8];
#pragma unroll
      for (int g4 = 0; g4 < 4; ++g4)
        acc[g4] = __builtin_amdgcn_mfma_f32_16x16x32_bf16(a, T[g4], acc[g4], 0, 0, 0);
    }
#pragma unroll
    for (int g4 = 0; g4 < 4; ++g4)
      T[g4] = *(const s16x8*)&wgl[(28 + g4) * 512];
    // kt6 (S)
    {
      s16x8 a = *(const s16x8*)&hr[cc * 264 + 6 * 32 + qq * 8];
#pragma unroll
      for (int g4 = 0; g4 < 4; ++g4)
        acc[g4] = __builtin_amdgcn_mfma_f32_16x16x32_bf16(a, S[g4], acc[g4], 0, 0, 0);
    }
    // kt7 (T)
    {
      s16x8 a = *(const s16x8*)&hr[cc * 264 + 7 * 32 + qq * 8];
#pragma unroll
      for (int g4 = 0; g4 < 4; ++g4)
        acc[g4] = __builtin_amdgcn_mfma_f32_16x16x32_bf16(a, T[g4], acc[g4], 0, 0, 0);
    }

    // epilogue: gxp retired long ago (older than kt4's loads)
#pragma unroll
    for (int r = 0; r < 4; ++r) {
      const int m = qq * 4 + r;
      const u32x2 pk = gxp[r];
      float gi = acc[0][r] + bf2f((unsigned short)(pk.x & 0xffff));
      float gf = acc[1][r] + bf2f((unsigned short)(pk.x >> 16));
      float gg = acc[2][r] + bf2f((unsigned short)(pk.y & 0xffff));
      float go = acc[3][r] + bf2f((unsigned short)(pk.y >> 16));
      if (t < lenr[r]) {
        float cn = sigm(gf) * cst[r] + sigm(gi) * tanh_(gg);
        cst[r] = cn;
        hreg[r] = f2bf(sigm(go) * tanh_(cn));
      }
      hw[m * 264 + j] = hreg[r];   // unconditional frozen carry
    }
  }

  // final h lives in hreg (frozen at each sequence's last valid step)
#pragma unroll
  for (int r = 0; r < 4; ++r)
    chunks[(size_t)sg[qq * 4 + r] * 512 + j] = bf2f(hreg[r]);
}

// ---------------------------------------------------------------------------
// K7: chunk BiLSTM. 4 blocks (2 dir x 2 m-groups of 16) x 1024 threads.
// Same 16-wave S/T streaming structure as tok_fwd.
__global__ __launch_bounds__(1024, 4)
void chunk_rec(const unsigned short* __restrict__ gxf,   // t-major [mg][32][16][1024]
               const unsigned short* __restrict__ gxb,
               const unsigned short* __restrict__ WhPf,
               const unsigned short* __restrict__ WhPb,
               const int* __restrict__ xlen,
               unsigned short* __restrict__ ch) {
  extern __shared__ unsigned short smem[];
  unsigned short* hbuf = smem;                // 2 x 4224 shorts
  unsigned short* ldsW = smem + 8448;         // 65536 shorts

  const int tid = threadIdx.x;
  const int lane = tid & 63, w = tid >> 6;
  const int cc = lane & 15, qq = lane >> 4;
  const int dir = blockIdx.x & 1, mg = blockIdx.x >> 1;
  const unsigned short* gx = (dir ? gxb : gxf) + (size_t)mg * 32 * 16 * 1024;
  const unsigned short* WhP = dir ? WhPb : WhPf;

  for (int i = tid; i < 8448; i += 1024) hbuf[i] = 0;

  const unsigned short* wgl = WhP + ((size_t)w * 8 * 4) * 512 + lane * 8;
  {
    unsigned short* ld = ldsW + w * 4096 + lane * 8;
#pragma unroll
    for (int s = 0; s < 8; ++s)
      *(s16x8*)&ld[s * 512] = *(const s16x8*)&wgl[s * 512];
  }
  __syncthreads();

  const int j = w * 16 + cc;
  int lenr[4];
#pragma unroll
  for (int r = 0; r < 4; ++r) {
    int L = xlen[mg * 16 + qq * 4 + r];
    lenr[r] = L > 32 ? 32 : L;
  }

  float cst[4];
  unsigned short hreg[4];
#pragma unroll
  for (int i = 0; i < 4; ++i) { cst[i] = 0.f; hreg[i] = 0; }

  const unsigned short* ldw = ldsW + w * 4096 + lane * 8;
  f32x4 zz = {0.f, 0.f, 0.f, 0.f};

  for (int tt = 0; tt < 32; ++tt) {
    const int t = dir ? (31 - tt) : tt;
    const unsigned short* hr = hbuf + (tt & 1) * 4224;
    unsigned short* hw = hbuf + ((tt & 1) ^ 1) * 4224;

    __syncthreads();

    s16x8 S[4], T[4];
#pragma unroll
    for (int g4 = 0; g4 < 4; ++g4)
      S[g4] = *(const s16x8*)&wgl[(8 + g4) * 512];
    u32x2 gxp[4];
#pragma unroll
    for (int r = 0; r < 4; ++r)
      gxp[r] = *(const u32x2*)(gx + ((size_t)t * 16 + qq * 4 + r) * 1024 + j * 4);
#pragma unroll
    for (int g4 = 0; g4 < 4; ++g4)
      T[g4] = *(const s16x8*)&wgl[(12 + g4) * 512];

    f32x4 acc[4];
#pragma unroll
    for (int g4 = 0; g4 < 4; ++g4) acc[g4] = zz;

#pragma unroll
    for (int kt = 0; kt < 2; ++kt) {
      s16x8 a = *(const s16x8*)&hr[cc * 264 + kt * 32 + qq * 8];
#pragma unroll
      for (int g4 = 0; g4 < 4; ++g4)
        acc[g4] = __builtin_amdgcn_mfma_f32_16x16x32_bf16(
            a, *(const s16x8*)&ldw[(kt * 4 + g4) * 512], acc[g4], 0, 0, 0);
    }
    {
      s16x8 a = *(const s16x8*)&hr[cc * 264 + 2 * 32 + qq * 8];
#pragma unroll
      for (int g4 = 0; g4 < 4; ++g4)
        acc[g4] = __builtin_amdgcn_mfma_f32_16x16x32_bf16(a, S[g4], acc[g4], 0, 0, 0);
    }
#pragma unroll
    for (int g4 = 0; g4 < 4; ++g4)
      S[g4] = *(const s16x8*)&wgl[(16 + g4) * 512];
    {
      s16x8 a = *(const s16x8*)&hr[cc * 264 + 3 * 32 + qq * 8];
#pragma unroll
      for (int g4 = 0; g4 < 4; ++g4)
        acc[g4] = __builtin_amdgcn_mfma_f32_16x16x32_bf16(a, T[g4], acc[g4], 0, 0, 0);
    }
#pragma unroll
    for (int g4 = 0; g4 < 4; ++g4)
      T[g4] = *(const s16x8*)&wgl[(20 + g4) * 512];
    {
      s16x8 a = *(const s16x8*)&hr[cc * 264 + 4 * 32 + qq * 8];
#pragma unroll
      for (int g4 = 0; g4 < 4; ++g4)
        acc[g4] = __builtin_amdgcn_mfma_f32_16x16x32_bf16(a, S[g4], acc[g4], 0, 0, 0);
    }
#pragma unroll
    for (int g4 = 0; g4 < 4; ++g4)
      S[g4] = *(const s16x8*)&wgl[(24 + g4) * 512];
    {
      s16x8 a = *(const s16x8*)&hr[cc * 264 + 5 * 32 + qq * 8];
#pragma unroll
      for (int g4 = 0; g4 < 4; ++g4)
        acc[g4] = __builtin_amdgcn_mfma_f32_16x16x32_bf16(a, T[g4], acc[g4], 0, 0, 0);
    }
#pragma unroll
    for (int g4 = 0; g4 < 4; ++g4)
      T[g4] = *(const s16x8*)&wgl[(28 + g4) * 512];
    {
      s16x8 a = *(const s16x8*)&hr[cc * 264 + 6 * 32 + qq * 8];
#pragma unroll
      for (int g4 = 0; g4 < 4; ++g4)
        acc[g4] = __builtin_amdgcn_mfma_f32_16x16x32_bf16(a, S[g4], acc[g4], 0, 0, 0);
    }
    {
      s16x8 a = *(const s16x8*)&hr[cc * 264 + 7 * 32 + qq * 8];
#pragma unroll
      for (int g4 = 0; g4 < 4; ++g4)
        acc[g4] = __builtin_amdgcn_mfma_f32_16x16x32_bf16(a, T[g4], acc[g4], 0, 0, 0);
    }

#pragma unroll
    for (int r = 0; r < 4; ++r) {
      const int m = qq * 4 + r;
      const u32x2 pk = gxp[r];
      float gi = acc[0][r] + bf2f((unsigned short)(pk.x & 0xffff));
      float gf = acc[1][r] + bf2f((unsigned short)(pk.x >> 16));
      float gg = acc[2][r] + bf2f((unsigned short)(pk.y & 0xffff));
      float go = acc[3][r] + bf2f((unsigned short)(pk.y >> 16));
      unsigned short out16 = 0;
      if (t < lenr[r]) {
        float cn = sigm(gf) * cst[r] + sigm(gi) * tanh_(gg);
        cst[r] = cn;
        hreg[r] = f2bf(sigm(go) * tanh_(cn));
        out16 = hreg[r];
      }
      hw[m * 264 + j] = hreg[r];   // frozen-state carry
      ch[(size_t)((mg * 16 + m) * 32 + t) * 512 + dir * 256 + j] = out16;
    }
  }
}

// ---------------------------------------------------------------------------
__global__ __launch_bounds__(64)
void fc_kernel(const unsigned short* __restrict__ ch, const float* __restrict__ W,
               const float* __restrict__ bfc, float* __restrict__ out) {
  const int n = blockIdx.x, lane = threadIdx.x;
  float xv[8];
  const unsigned short* cp = ch + (long)n * 512 + lane * 8;
#pragma unroll
  for (int i = 0; i < 8; ++i) xv[i] = bf2f(cp[i]);
  float s[9];
#pragma unroll
  for (int k = 0; k < 9; ++k) {
    const float* wr = W + k * 512 + lane * 8;
    float t = 0.f;
#pragma unroll
    for (int i = 0; i < 8; ++i) t += xv[i] * wr[i];
    s[k] = t;
  }
#pragma unroll
  for (int off = 32; off; off >>= 1)
#pragma unroll
    for (int k = 0; k < 9; ++k) s[k] += __shfl_down(s[k], off, 64);
  if (lane == 0) {
#pragma unroll
    for (int k = 0; k < 9; ++k) out[n * 9 + k] = s[k] + bfc[k];
  }
}

// ---------------------------------------------------------------------------
extern "C" void kernel_launch(void* const* d_in, const int* in_sizes, int n_in,
                              void* d_out, int out_size, void* d_ws, size_t ws_size,
                              hipStream_t stream) {
  const int*   x           = (const int*)d_in[0];
  const int*   x_len       = (const int*)d_in[2];
  const int*   x_chunk_len = (const int*)d_in[3];
  const float* emb         = (const float*)d_in[4];
  const float* tok_Wih_f   = (const float*)d_in[5];
  const float* tok_Whh_f   = (const float*)d_in[6];
  const float* tok_b_f     = (const float*)d_in[7];
  const float* tok_Wih_b   = (const float*)d_in[8];
  // d_in[9] tok_Whh_b: unused (reverse masked scan at t=clen-1 starts from zero state)
  const float* tok_b_b     = (const float*)d_in[10];
  const float* chk_Wih_f   = (const float*)d_in[11];
  const float* chk_Whh_f   = (const float*)d_in[12];
  const float* chk_b_f     = (const float*)d_in[13];
  const float* chk_Wih_b   = (const float*)d_in[14];
  const float* chk_Whh_b   = (const float*)d_in[15];
  const float* chk_b_b     = (const float*)d_in[16];
  const float* fc_W        = (const float*)d_in[17];
  const float* fc_b        = (const float*)d_in[18];
  float* out = (float*)d_out;

  char* ws = (char*)d_ws;
  size_t off = 0;
  auto alloc = [&](size_t bytes) -> void* {
    void* p = ws + off;
    off += (bytes + 255) & ~(size_t)255;
    return p;
  };
  unsigned short* Wf   = (unsigned short*)alloc((size_t)1024 * 320 * 2);
  unsigned short* Wb   = (unsigned short*)alloc((size_t)1024 * 320 * 2);
  unsigned short* Wcf  = (unsigned short*)alloc((size_t)1024 * 512 * 2);
  unsigned short* Wcb  = (unsigned short*)alloc((size_t)1024 * 512 * 2);
  unsigned short* WhPtok=(unsigned short*)alloc((size_t)512 * 512 * 2);   // frag-major
  unsigned short* WhPcf= (unsigned short*)alloc((size_t)512 * 512 * 2);
  unsigned short* WhPcb= (unsigned short*)alloc((size_t)512 * 512 * 2);
  unsigned short* proj = (unsigned short*)alloc((size_t)30000 * 1024 * 2);
  unsigned short* gxbb = (unsigned short*)alloc((size_t)1024 * 1024 * 2);
  unsigned short* gxcf = (unsigned short*)alloc((size_t)1024 * 1024 * 2);
  unsigned short* gxcb = (unsigned short*)alloc((size_t)1024 * 1024 * 2);
  unsigned short* gxcfp= (unsigned short*)alloc((size_t)1024 * 1024 * 2);
  unsigned short* gxcbp= (unsigned short*)alloc((size_t)1024 * 1024 * 2);
  float*          chunks = (float*)alloc((size_t)1024 * 512 * 4);
  unsigned short* cho  = (unsigned short*)alloc((size_t)1024 * 512 * 2);
  unsigned short* gxs  = (unsigned short*)alloc((size_t)1024 * 64 * 1024 * 2);  // 134 MB
  int* clens = (int*)alloc(1024 * 4);
  int* lastv = (int*)alloc(1024 * 4);
  int* order = (int*)alloc(1024 * 4);
  int* glen  = (int*)alloc(64 * 4);

  // allow >64 KB dynamic LDS for the recurrent kernels (gfx950: 160 KB/CU)
  hipFuncSetAttribute((const void*)tok_fwd,
                      hipFuncAttributeMaxDynamicSharedMemorySize, 148096);
  hipFuncSetAttribute((const void*)chunk_rec,
                      hipFuncAttributeMaxDynamicSharedMemorySize, 147968);

  prep_weights<<<dim3(1024, 4), 256, 0, stream>>>(
      tok_Wih_f, tok_Wih_b, chk_Wih_f, chk_Wih_b, Wf, Wb, Wcf, Wcb);
  prep_whh_frag<<<dim3(512, 3), 256, 0, stream>>>(
      tok_Whh_f, chk_Whh_f, chk_Whh_b, WhPtok, WhPcf, WhPcb);
  prep_small<<<1, 1024, 0, stream>>>(x, x_chunk_len, clens, lastv, order, glen);

  // vocab pre-projection: proj = emb x tok_Wih_f^T
  gemm_bf<<<dim3(4, 235), 256, 0, stream>>>(emb, nullptr, 30000, 300, 300, 320, Wf, proj);
  // backward gx for last tokens only
  gemm_bf<<<dim3(4, 8), 256, 0, stream>>>(emb, lastv, 1024, 300, 300, 320, Wb, gxbb);
  bwd_step<<<1024, 256, 0, stream>>>(gxbb, tok_b_b, chunks);
  // pre-gather forward gate projections (gate-packed, bias folded, t-major/16)
  gather_gx<<<dim3(64, 1024), 256, 0, stream>>>(proj, x, order, clens, glen, tok_b_f, gxs);
  // forward token recurrence: 64 blocks x 16 seqs x 16 waves
  tok_fwd<<<64, 1024, 148096, stream>>>(gxs, WhPtok, order, clens, glen, chunks);
  // chunk-level input projections
  gemm_bf<<<dim3(4, 8), 256, 0, stream>>>(chunks, nullptr, 1024, 512, 512, 512, Wcf, gxcf);
  gemm_bf<<<dim3(4, 8), 256, 0, stream>>>(chunks, nullptr, 1024, 512, 512, 512, Wcb, gxcb);
  repack4<<<dim3(1024, 2), 256, 0, stream>>>(gxcf, gxcb, chk_b_f, chk_b_b, gxcfp, gxcbp);
  // chunk BiLSTM: 4 blocks (2 dir x 2 m-groups) x 16 waves
  chunk_rec<<<4, 1024, 147968, stream>>>(gxcfp, gxcbp, WhPcf, WhPcb, x_len, cho);
  // final FC
  fc_kernel<<<1024, 64, 0, stream>>>(cho, fc_W, fc_b, out);
}

// Round 9
// 931.504 us; speedup vs baseline: 1.0644x; 1.0021x over previous
//
#include <hip/hip_runtime.h>

// ---------------------------------------------------------------------------
// HierarchicalBiLSTM_CRF on MI355X (gfx950) — round 17
//
// Round-17: r16 + amdgpu_waves_per_eu(4,4) on the recurrent kernels.
// r16 measured VGPR_Count=64: with only launch_bounds(1024,4) (a MINIMUM),
// the allocator targeted 8 waves/EU (64-reg budget) and spilled the S/T
// stream buffers — even though the 148KB LDS already caps the CU at
// 1 block = 4 waves/EU. Pinning min=max=4 makes the 128-reg budget free,
// and the r16 loop working set (~95 regs: acc 16 + S/T 32 + gx 8 + misc)
// fits, so the double-buffer should finally survive allocation.
// Everything else is byte-identical to r16 (which passed, absmax 9.8e-4).
// Diagnostic: VGPR stays 64 -> attribute dead -> next round reverts to r14
// skeleton and attacks gather_gx / gemm instead.
// ---------------------------------------------------------------------------

typedef __attribute__((ext_vector_type(8))) short s16x8;
typedef __attribute__((ext_vector_type(4))) float f32x4;
typedef __attribute__((ext_vector_type(2))) unsigned int u32x2;
typedef __attribute__((ext_vector_type(4))) unsigned int u32x4;

__device__ __forceinline__ unsigned short f2bf(float f) {
  unsigned u = __builtin_bit_cast(unsigned, f);
  u += 0x7fff + ((u >> 16) & 1);   // RNE
  return (unsigned short)(u >> 16);
}
__device__ __forceinline__ float bf2f(unsigned short h) {
  unsigned u = ((unsigned)h) << 16;
  return __builtin_bit_cast(float, u);
}
__device__ __forceinline__ float sigm(float x) { return 1.f / (1.f + __expf(-x)); }
__device__ __forceinline__ float tanh_(float x) { return 1.f - 2.f / (__expf(2.f * x) + 1.f); }

union PK8 { s16x8 v; unsigned short u[8]; };

// ---------------------------------------------------------------------------
// K0a: cast input-projection weights to bf16 (pad K 300->320 for token Wih)
__global__ void prep_weights(const float* __restrict__ wihf, const float* __restrict__ wihb,
                             const float* __restrict__ wcf, const float* __restrict__ wcb,
                             unsigned short* __restrict__ o_wf, unsigned short* __restrict__ o_wb,
                             unsigned short* __restrict__ o_wcf, unsigned short* __restrict__ o_wcb) {
  const int job = blockIdx.y, r = blockIdx.x, tid = threadIdx.x;
  const float* src; unsigned short* dst; int Ks, Kd;
  switch (job) {
    case 0: src = wihf; dst = o_wf;   Ks = 300; Kd = 320; break;
    case 1: src = wihb; dst = o_wb;   Ks = 300; Kd = 320; break;
    case 2: src = wcf;  dst = o_wcf;  Ks = 512; Kd = 512; break;
    default:src = wcb;  dst = o_wcb;  Ks = 512; Kd = 512; break;
  }
  for (int c = tid; c < Kd; c += 256)
    dst[r * Kd + c] = f2bf(c < Ks ? src[r * Ks + c] : 0.f);
}

// ---------------------------------------------------------------------------
// K0c: repack recurrent weights [1024][256] f32 -> fragment-major bf16.
// fid = (jt*8 + kt)*4 + g  (jt = j-tile 0..15, kt = k-section 0..7, g = gate)
__global__ __launch_bounds__(256)
void prep_whh_frag(const float* __restrict__ w0, const float* __restrict__ w1,
                   const float* __restrict__ w2,
                   unsigned short* __restrict__ o0, unsigned short* __restrict__ o1,
                   unsigned short* __restrict__ o2) {
  const float* src = blockIdx.y == 0 ? w0 : (blockIdx.y == 1 ? w1 : w2);
  unsigned short* dst = blockIdx.y == 0 ? o0 : (blockIdx.y == 1 ? o1 : o2);
  const int fid = blockIdx.x;
  const int g = fid & 3, kt = (fid >> 2) & 7, jt = fid >> 5;
  for (int i = threadIdx.x; i < 512; i += 256) {
    const int lane = i >> 3, e = i & 7;
    const int cc = lane & 15, qq = lane >> 4;
    const int row = g * 256 + jt * 16 + cc;
    const int col = kt * 32 + qq * 8 + e;
    dst[(size_t)fid * 512 + i] = f2bf(src[row * 256 + col]);
  }
}

// ---------------------------------------------------------------------------
__global__ void prep_small(const int* __restrict__ x, const int* __restrict__ xcl,
                           int* __restrict__ clens, int* __restrict__ lastv,
                           int* __restrict__ order, int* __restrict__ glen) {
  __shared__ int start[65];
  const int n = threadIdx.x;  // 1024 threads
  if (n < 65) start[n] = 0;
  __syncthreads();
  int len = xcl[n]; len = len < 1 ? 1 : (len > 64 ? 64 : len);
  clens[n] = len;
  lastv[n] = x[n * 64 + len - 1];
  atomicAdd(&start[len], 1);
  __syncthreads();
  if (n == 0) {
    int acc = 0;
    for (int l = 64; l >= 1; --l) { int h = start[l]; start[l] = acc; acc += h; }
  }
  __syncthreads();
  int pos = atomicAdd(&start[len], 1);
  order[pos] = n;
  __syncthreads();
  if (n < 64) glen[n] = clens[order[n * 16]];   // descending -> 16-group max
}

// ---------------------------------------------------------------------------
// Unified GEMM: C[M][1024](bf16) = A(rows via rowmap)[M][Klog](f32) x B[1024][KP](bf16)^T
__global__ __launch_bounds__(256, 2)
void gemm_bf(const float* __restrict__ A, const int* __restrict__ rowmap,
             int Mrows, int Astride, int Klog, int KP,
             const unsigned short* __restrict__ B, unsigned short* __restrict__ C) {
  __shared__ unsigned short As[128 * 40];
  __shared__ unsigned short Ep[4][64 * 136];
  const int tid = threadIdx.x;
  const int lane = tid & 63, w = tid >> 6;
  const int wrow = w >> 1, wcol = w & 1;
  const int cc = lane & 15, qq = lane >> 4;
  const int m0 = blockIdx.y * 128, n0 = blockIdx.x * 256;

  f32x4 zz = {0.f, 0.f, 0.f, 0.f};
  f32x4 acc[4][8];
#pragma unroll
  for (int i = 0; i < 4; ++i)
#pragma unroll
    for (int j = 0; j < 8; ++j) acc[i][j] = zz;

  const int arow = tid >> 1, ahalf = tid & 1;
  const float* arp = nullptr;
  {
    int av = m0 + arow;
    if (av < Mrows) {
      int amap = rowmap ? rowmap[av] : av;
      arp = A + (long)amap * Astride;
    }
  }

  const int nktiles = KP >> 5;
  for (int kt = 0; kt < nktiles; ++kt) {
    const int k0 = kt << 5;
    __syncthreads();
    {
      const int kb = k0 + ahalf * 16;
      unsigned short hv[16];
      if (arp && kb + 16 <= Klog) {
        const float* p = arp + kb;
#pragma unroll
        for (int i = 0; i < 16; i += 4) {
          f32x4 t = *(const f32x4*)(p + i);
          hv[i] = f2bf(t.x); hv[i + 1] = f2bf(t.y);
          hv[i + 2] = f2bf(t.z); hv[i + 3] = f2bf(t.w);
        }
      } else {
#pragma unroll
        for (int i = 0; i < 16; ++i) {
          float v = (arp && (kb + i) < Klog) ? arp[kb + i] : 0.f;
          hv[i] = f2bf(v);
        }
      }
      PK8 p0, p1;
#pragma unroll
      for (int i = 0; i < 8; ++i) { p0.u[i] = hv[i]; p1.u[i] = hv[8 + i]; }
      *(s16x8*)&As[arow * 40 + ahalf * 16] = p0.v;
      *(s16x8*)&As[arow * 40 + ahalf * 16 + 8] = p1.v;
    }
    __syncthreads();
    s16x8 af[4];
#pragma unroll
    for (int mt = 0; mt < 4; ++mt)
      af[mt] = *(const s16x8*)&As[(wrow * 64 + mt * 16 + cc) * 40 + qq * 8];
#pragma unroll
    for (int nt = 0; nt < 8; ++nt) {
      const unsigned short* bp = B + (long)(n0 + wcol * 128 + nt * 16 + cc) * KP + k0 + qq * 8;
      s16x8 bfr = *(const s16x8*)bp;
#pragma unroll
      for (int mt = 0; mt < 4; ++mt)
        acc[mt][nt] = __builtin_amdgcn_mfma_f32_16x16x32_bf16(af[mt], bfr, acc[mt][nt], 0, 0, 0);
    }
  }
  __syncthreads();
#pragma unroll
  for (int mt = 0; mt < 4; ++mt)
#pragma unroll
    for (int nt = 0; nt < 8; ++nt)
#pragma unroll
      for (int r = 0; r < 4; ++r)
        Ep[w][(mt * 16 + qq * 4 + r) * 136 + nt * 16 + cc] = f2bf(acc[mt][nt][r]);
  __syncthreads();
#pragma unroll
  for (int it = 0; it < 16; ++it) {
    int row = it * 4 + qq;
    s16x8 d = *(const s16x8*)&Ep[w][row * 136 + cc * 8];
    int gm = m0 + wrow * 64 + row;
    int gn = n0 + wcol * 128 + cc * 8;
    if (gm < Mrows) *(s16x8*)&C[(long)gm * 1024 + gn] = d;
  }
}

// ---------------------------------------------------------------------------
__global__ void bwd_step(const unsigned short* __restrict__ gxb,
                         const float* __restrict__ bias,
                         float* __restrict__ chunks) {
  const int n = blockIdx.x, j = threadIdx.x;  // 1024 x 256
  const unsigned short* row = gxb + (long)n * 1024;
  float gi = bf2f(row[j]) + bias[j];
  float gg = bf2f(row[512 + j]) + bias[512 + j];
  float go = bf2f(row[768 + j]) + bias[768 + j];
  float cn = sigm(gi) * tanh_(gg);
  chunks[(long)n * 512 + 256 + j] = sigm(go) * tanh_(cn);
}

// ---------------------------------------------------------------------------
// K4: pre-gather gate projections (gate-packed j*4+g, bias folded), sorted
// order, T-MAJOR per 16-group: gx[g16][t][m16][j*4+g]. Pad steps unwritten.
__global__ __launch_bounds__(256)
void gather_gx(const unsigned short* __restrict__ proj, const int* __restrict__ x,
               const int* __restrict__ order, const int* __restrict__ clens,
               const int* __restrict__ glen, const float* __restrict__ bias,
               unsigned short* __restrict__ gx) {
  const int t = blockIdx.x, p = blockIdx.y, j = threadIdx.x;
  if (t >= glen[p >> 4]) return;
  const int seq = order[p];
  const int len = clens[seq];
  if (t >= len) return;
  unsigned short* dst = gx + (((size_t)(p >> 4) * 64 + t) * 16 + (p & 15)) * 1024 + j * 4;
  const int tok = x[seq * 64 + t];
  const unsigned short* src = proj + (size_t)tok * 1024 + j;
  unsigned v0 = f2bf(bf2f(src[0]) + bias[j]);
  unsigned v1 = f2bf(bf2f(src[256]) + bias[256 + j]);
  unsigned v2 = f2bf(bf2f(src[512]) + bias[512 + j]);
  unsigned v3 = f2bf(bf2f(src[768]) + bias[768 + j]);
  u32x2 pk = {v0 | (v1 << 16), v2 | (v3 << 16)};
  *(u32x2*)dst = pk;
}

// ---------------------------------------------------------------------------
// K6b: gate-pack gxc with bias folded, T-MAJOR per 16-group, j*4+g layout.
__global__ __launch_bounds__(256)
void repack4(const unsigned short* __restrict__ s0, const unsigned short* __restrict__ s1,
             const float* __restrict__ b0, const float* __restrict__ b1,
             unsigned short* __restrict__ d0, unsigned short* __restrict__ d1) {
  const int r = blockIdx.x, j = threadIdx.x;
  const int m = r >> 5, t = r & 31;
  const int mg = m >> 4, m16 = m & 15;
  const unsigned short* s = (blockIdx.y ? s1 : s0) + (size_t)r * 1024;
  const float* bb = blockIdx.y ? b1 : b0;
  unsigned short* d = (blockIdx.y ? d1 : d0) +
                      (size_t)((mg * 32 + t) * 16 + m16) * 1024 + j * 4;
  unsigned v0 = f2bf(bf2f(s[j]) + bb[j]);
  unsigned v1 = f2bf(bf2f(s[256 + j]) + bb[256 + j]);
  unsigned v2 = f2bf(bf2f(s[512 + j]) + bb[512 + j]);
  unsigned v3 = f2bf(bf2f(s[768 + j]) + bb[768 + j]);
  u32x2 pk = {v0 | (v1 << 16), v2 | (v3 << 16)};
  *(u32x2*)d = pk;
}

// ---------------------------------------------------------------------------
// K5: forward token LSTM. 64 blocks x 16 seqs x 1024 threads (16 waves x
// 16 j-cols). waves_per_eu(4,4): LDS already caps at 1 block/CU = 4 waves/EU;
// pinning makes the 128-reg budget free so S/T double-buffer survives RA.
// kt0-1 LDS; kt2-7 streamed S[4]/T[4]; gx issued between kt2/kt3.
__global__ __launch_bounds__(1024, 4) __attribute__((amdgpu_waves_per_eu(4, 4)))
void tok_fwd(const unsigned short* __restrict__ gx,     // [g16][64][16][1024]
             const unsigned short* __restrict__ WhP,    // frag-major (jt,kt,g)
             const int* __restrict__ order,
             const int* __restrict__ clens,
             const int* __restrict__ glen,
             float* __restrict__ chunks) {
  extern __shared__ unsigned short smem[];
  unsigned short* hbuf = smem;                // 2 x [16][264] = 8448 shorts
  unsigned short* ldsW = smem + 8448;         // 16 waves * 4096 shorts = 128 KB
  int* sg = (int*)(smem + 8448 + 65536);      // [16]
  int* slen = sg + 16;                        // [16]

  const int tid = threadIdx.x;
  const int lane = tid & 63, w = tid >> 6;    // w in 0..15
  const int cc = lane & 15, qq = lane >> 4;
  const int gb = blockIdx.x;

  if (tid < 16) {
    int s = order[gb * 16 + tid];
    sg[tid] = s;
    slen[tid] = clens[s];
  }
  for (int i = tid; i < 8448; i += 1024) hbuf[i] = 0;   // zero t=0 read buffer

  // wave w (j-tile jt=w): frag (kt,g) at ((w*8+kt)*4+g)*512
  const unsigned short* wgl = WhP + ((size_t)w * 8 * 4) * 512 + lane * 8;
  {
    unsigned short* ld = ldsW + w * 4096 + lane * 8;
#pragma unroll
    for (int s = 0; s < 8; ++s)              // kt0-1 x 4 gates
      *(s16x8*)&ld[s * 512] = *(const s16x8*)&wgl[s * 512];
  }
  __syncthreads();

  const int maxlen = glen[gb];
  int lenr[4];
#pragma unroll
  for (int r = 0; r < 4; ++r) lenr[r] = slen[qq * 4 + r];

  float cst[4];
  unsigned short hreg[4];
#pragma unroll
  for (int i = 0; i < 4; ++i) { cst[i] = 0.f; hreg[i] = 0; }

  const int j = w * 16 + cc;
  const unsigned short* gx0 = gx + (size_t)gb * 64 * 16 * 1024 + j * 4;
  const unsigned short* ldw = ldsW + w * 4096 + lane * 8;
  f32x4 zz = {0.f, 0.f, 0.f, 0.f};

  for (int t = 0; t < maxlen; ++t) {
    const unsigned short* hr = hbuf + (t & 1) * 4224;        // read h(t-1)
    unsigned short* hw = hbuf + ((t & 1) ^ 1) * 4224;        // write h(t)

    __syncthreads();   // prev-step hw writes visible

    // issue: S<-kt2 (oldest), gx, T<-kt3 — one section always in flight.
    s16x8 S[4], T[4];
#pragma unroll
    for (int g4 = 0; g4 < 4; ++g4)
      S[g4] = *(const s16x8*)&wgl[(8 + g4) * 512];
    u32x2 gxp[4];
#pragma unroll
    for (int r = 0; r < 4; ++r)
      gxp[r] = *(const u32x2*)(gx0 + ((size_t)t * 16 + qq * 4 + r) * 1024);
#pragma unroll
    for (int g4 = 0; g4 < 4; ++g4)
      T[g4] = *(const s16x8*)&wgl[(12 + g4) * 512];

    f32x4 acc[4];
#pragma unroll
    for (int g4 = 0; g4 < 4; ++g4) acc[g4] = zz;

    // kt0-1 from LDS (covers S/T flight time)
#pragma unroll
    for (int kt = 0; kt < 2; ++kt) {
      s16x8 a = *(const s16x8*)&hr[cc * 264 + kt * 32 + qq * 8];
#pragma unroll
      for (int g4 = 0; g4 < 4; ++g4)
        acc[g4] = __builtin_amdgcn_mfma_f32_16x16x32_bf16(
            a, *(const s16x8*)&ldw[(kt * 4 + g4) * 512], acc[g4], 0, 0, 0);
    }
    // kt2 (S) -> refill S<-kt4
    {
      s16x8 a = *(const s16x8*)&hr[cc * 264 + 2 * 32 + qq * 8];
#pragma unroll
      for (int g4 = 0; g4 < 4; ++g4)
        acc[g4] = __builtin_amdgcn_mfma_f32_16x16x32_bf16(a, S[g4], acc[g4], 0, 0, 0);
    }
#pragma unroll
    for (int g4 = 0; g4 < 4; ++g4)
      S[g4] = *(const s16x8*)&wgl[(16 + g4) * 512];
    // kt3 (T) -> refill T<-kt5
    {
      s16x8 a = *(const s16x8*)&hr[cc * 264 + 3 * 32 + qq * 8];
#pragma unroll
      for (int g4 = 0; g4 < 4; ++g4)
        acc[g4] = __builtin_amdgcn_mfma_f32_16x16x32_bf16(a, T[g4], acc[g4], 0, 0, 0);
    }
#pragma unroll
    for (int g4 = 0; g4 < 4; ++g4)
      T[g4] = *(const s16x8*)&wgl[(20 + g4) * 512];
    // kt4 (S) -> refill S<-kt6
    {
      s16x8 a = *(const s16x8*)&hr[cc * 264 + 4 * 32 + qq * 8];
#pragma unroll
      for (int g4 = 0; g4 < 4; ++g4)
        acc[g4] = __builtin_amdgcn_mfma_f32_16x16x32_bf16(a, S[g4], acc[g4], 0, 0, 0);
    }
#pragma unroll
    for (int g4 = 0; g4 < 4; ++g4)
      S[g4] = *(const s16x8*)&wgl[(24 + g4) * 512];
    // kt5 (T) -> refill T<-kt7
    {
      s16x8 a = *(const s16x8*)&hr[cc * 264 + 5 * 32 + qq * 8];
#pragma unroll
      for (int g4 = 0; g4 < 4; ++g4)
        acc[g4] = __builtin_amdgcn_mfma_f32_16x16x32_bf16(a, T[g4], acc[g4], 0, 0, 0);
    }
#pragma unroll
    for (int g4 = 0; g4 < 4; ++g4)
      T[g4] = *(const s16x8*)&wgl[(28 + g4) * 512];
    // kt6 (S)
    {
      s16x8 a = *(const s16x8*)&hr[cc * 264 + 6 * 32 + qq * 8];
#pragma unroll
      for (int g4 = 0; g4 < 4; ++g4)
        acc[g4] = __builtin_amdgcn_mfma_f32_16x16x32_bf16(a, S[g4], acc[g4], 0, 0, 0);
    }
    // kt7 (T)
    {
      s16x8 a = *(const s16x8*)&hr[cc * 264 + 7 * 32 + qq * 8];
#pragma unroll
      for (int g4 = 0; g4 < 4; ++g4)
        acc[g4] = __builtin_amdgcn_mfma_f32_16x16x32_bf16(a, T[g4], acc[g4], 0, 0, 0);
    }

    // epilogue: gxp retired long ago (older than kt4's loads)
#pragma unroll
    for (int r = 0; r < 4; ++r) {
      const int m = qq * 4 + r;
      const u32x2 pk = gxp[r];
      float gi = acc[0][r] + bf2f((unsigned short)(pk.x & 0xffff));
      float gf = acc[1][r] + bf2f((unsigned short)(pk.x >> 16));
      float gg = acc[2][r] + bf2f((unsigned short)(pk.y & 0xffff));
      float go = acc[3][r] + bf2f((unsigned short)(pk.y >> 16));
      if (t < lenr[r]) {
        float cn = sigm(gf) * cst[r] + sigm(gi) * tanh_(gg);
        cst[r] = cn;
        hreg[r] = f2bf(sigm(go) * tanh_(cn));
      }
      hw[m * 264 + j] = hreg[r];   // unconditional frozen carry
    }
  }

  // final h lives in hreg (frozen at each sequence's last valid step)
#pragma unroll
  for (int r = 0; r < 4; ++r)
    chunks[(size_t)sg[qq * 4 + r] * 512 + j] = bf2f(hreg[r]);
}

// ---------------------------------------------------------------------------
// K7: chunk BiLSTM. 4 blocks (2 dir x 2 m-groups of 16) x 1024 threads.
// Same 16-wave S/T streaming structure + waves_per_eu(4,4).
__global__ __launch_bounds__(1024, 4) __attribute__((amdgpu_waves_per_eu(4, 4)))
void chunk_rec(const unsigned short* __restrict__ gxf,   // t-major [mg][32][16][1024]
               const unsigned short* __restrict__ gxb,
               const unsigned short* __restrict__ WhPf,
               const unsigned short* __restrict__ WhPb,
               const int* __restrict__ xlen,
               unsigned short* __restrict__ ch) {
  extern __shared__ unsigned short smem[];
  unsigned short* hbuf = smem;                // 2 x 4224 shorts
  unsigned short* ldsW = smem + 8448;         // 65536 shorts

  const int tid = threadIdx.x;
  const int lane = tid & 63, w = tid >> 6;
  const int cc = lane & 15, qq = lane >> 4;
  const int dir = blockIdx.x & 1, mg = blockIdx.x >> 1;
  const unsigned short* gx = (dir ? gxb : gxf) + (size_t)mg * 32 * 16 * 1024;
  const unsigned short* WhP = dir ? WhPb : WhPf;

  for (int i = tid; i < 8448; i += 1024) hbuf[i] = 0;

  const unsigned short* wgl = WhP + ((size_t)w * 8 * 4) * 512 + lane * 8;
  {
    unsigned short* ld = ldsW + w * 4096 + lane * 8;
#pragma unroll
    for (int s = 0; s < 8; ++s)
      *(s16x8*)&ld[s * 512] = *(const s16x8*)&wgl[s * 512];
  }
  __syncthreads();

  const int j = w * 16 + cc;
  int lenr[4];
#pragma unroll
  for (int r = 0; r < 4; ++r) {
    int L = xlen[mg * 16 + qq * 4 + r];
    lenr[r] = L > 32 ? 32 : L;
  }

  float cst[4];
  unsigned short hreg[4];
#pragma unroll
  for (int i = 0; i < 4; ++i) { cst[i] = 0.f; hreg[i] = 0; }

  const unsigned short* ldw = ldsW + w * 4096 + lane * 8;
  f32x4 zz = {0.f, 0.f, 0.f, 0.f};

  for (int tt = 0; tt < 32; ++tt) {
    const int t = dir ? (31 - tt) : tt;
    const unsigned short* hr = hbuf + (tt & 1) * 4224;
    unsigned short* hw = hbuf + ((tt & 1) ^ 1) * 4224;

    __syncthreads();

    s16x8 S[4], T[4];
#pragma unroll
    for (int g4 = 0; g4 < 4; ++g4)
      S[g4] = *(const s16x8*)&wgl[(8 + g4) * 512];
    u32x2 gxp[4];
#pragma unroll
    for (int r = 0; r < 4; ++r)
      gxp[r] = *(const u32x2*)(gx + ((size_t)t * 16 + qq * 4 + r) * 1024 + j * 4);
#pragma unroll
    for (int g4 = 0; g4 < 4; ++g4)
      T[g4] = *(const s16x8*)&wgl[(12 + g4) * 512];

    f32x4 acc[4];
#pragma unroll
    for (int g4 = 0; g4 < 4; ++g4) acc[g4] = zz;

#pragma unroll
    for (int kt = 0; kt < 2; ++kt) {
      s16x8 a = *(const s16x8*)&hr[cc * 264 + kt * 32 + qq * 8];
#pragma unroll
      for (int g4 = 0; g4 < 4; ++g4)
        acc[g4] = __builtin_amdgcn_mfma_f32_16x16x32_bf16(
            a, *(const s16x8*)&ldw[(kt * 4 + g4) * 512], acc[g4], 0, 0, 0);
    }
    {
      s16x8 a = *(const s16x8*)&hr[cc * 264 + 2 * 32 + qq * 8];
#pragma unroll
      for (int g4 = 0; g4 < 4; ++g4)
        acc[g4] = __builtin_amdgcn_mfma_f32_16x16x32_bf16(a, S[g4], acc[g4], 0, 0, 0);
    }
#pragma unroll
    for (int g4 = 0; g4 < 4; ++g4)
      S[g4] = *(const s16x8*)&wgl[(16 + g4) * 512];
    {
      s16x8 a = *(const s16x8*)&hr[cc * 264 + 3 * 32 + qq * 8];
#pragma unroll
      for (int g4 = 0; g4 < 4; ++g4)
        acc[g4] = __builtin_amdgcn_mfma_f32_16x16x32_bf16(a, T[g4], acc[g4], 0, 0, 0);
    }
#pragma unroll
    for (int g4 = 0; g4 < 4; ++g4)
      T[g4] = *(const s16x8*)&wgl[(20 + g4) * 512];
    {
      s16x8 a = *(const s16x8*)&hr[cc * 264 + 4 * 32 + qq * 8];
#pragma unroll
      for (int g4 = 0; g4 < 4; ++g4)
        acc[g4] = __builtin_amdgcn_mfma_f32_16x16x32_bf16(a, S[g4], acc[g4], 0, 0, 0);
    }
#pragma unroll
    for (int g4 = 0; g4 < 4; ++g4)
      S[g4] = *(const s16x8*)&wgl[(24 + g4) * 512];
    {
      s16x8 a = *(const s16x8*)&hr[cc * 264 + 5 * 32 + qq * 8];
#pragma unroll
      for (int g4 = 0; g4 < 4; ++g4)
        acc[g4] = __builtin_amdgcn_mfma_f32_16x16x32_bf16(a, T[g4], acc[g4], 0, 0, 0);
    }
#pragma unroll
    for (int g4 = 0; g4 < 4; ++g4)
      T[g4] = *(const s16x8*)&wgl[(28 + g4) * 512];
    {
      s16x8 a = *(const s16x8*)&hr[cc * 264 + 6 * 32 + qq * 8];
#pragma unroll
      for (int g4 = 0; g4 < 4; ++g4)
        acc[g4] = __builtin_amdgcn_mfma_f32_16x16x32_bf16(a, S[g4], acc[g4], 0, 0, 0);
    }
    {
      s16x8 a = *(const s16x8*)&hr[cc * 264 + 7 * 32 + qq * 8];
#pragma unroll
      for (int g4 = 0; g4 < 4; ++g4)
        acc[g4] = __builtin_amdgcn_mfma_f32_16x16x32_bf16(a, T[g4], acc[g4], 0, 0, 0);
    }

#pragma unroll
    for (int r = 0; r < 4; ++r) {
      const int m = qq * 4 + r;
      const u32x2 pk = gxp[r];
      float gi = acc[0][r] + bf2f((unsigned short)(pk.x & 0xffff));
      float gf = acc[1][r] + bf2f((unsigned short)(pk.x >> 16));
      float gg = acc[2][r] + bf2f((unsigned short)(pk.y & 0xffff));
      float go = acc[3][r] + bf2f((unsigned short)(pk.y >> 16));
      unsigned short out16 = 0;
      if (t < lenr[r]) {
        float cn = sigm(gf) * cst[r] + sigm(gi) * tanh_(gg);
        cst[r] = cn;
        hreg[r] = f2bf(sigm(go) * tanh_(cn));
        out16 = hreg[r];
      }
      hw[m * 264 + j] = hreg[r];   // frozen-state carry
      ch[(size_t)((mg * 16 + m) * 32 + t) * 512 + dir * 256 + j] = out16;
    }
  }
}

// ---------------------------------------------------------------------------
__global__ __launch_bounds__(64)
void fc_kernel(const unsigned short* __restrict__ ch, const float* __restrict__ W,
               const float* __restrict__ bfc, float* __restrict__ out) {
  const int n = blockIdx.x, lane = threadIdx.x;
  float xv[8];
  const unsigned short* cp = ch + (long)n * 512 + lane * 8;
#pragma unroll
  for (int i = 0; i < 8; ++i) xv[i] = bf2f(cp[i]);
  float s[9];
#pragma unroll
  for (int k = 0; k < 9; ++k) {
    const float* wr = W + k * 512 + lane * 8;
    float t = 0.f;
#pragma unroll
    for (int i = 0; i < 8; ++i) t += xv[i] * wr[i];
    s[k] = t;
  }
#pragma unroll
  for (int off = 32; off; off >>= 1)
#pragma unroll
    for (int k = 0; k < 9; ++k) s[k] += __shfl_down(s[k], off, 64);
  if (lane == 0) {
#pragma unroll
    for (int k = 0; k < 9; ++k) out[n * 9 + k] = s[k] + bfc[k];
  }
}

// ---------------------------------------------------------------------------
extern "C" void kernel_launch(void* const* d_in, const int* in_sizes, int n_in,
                              void* d_out, int out_size, void* d_ws, size_t ws_size,
                              hipStream_t stream) {
  const int*   x           = (const int*)d_in[0];
  const int*   x_len       = (const int*)d_in[2];
  const int*   x_chunk_len = (const int*)d_in[3];
  const float* emb         = (const float*)d_in[4];
  const float* tok_Wih_f   = (const float*)d_in[5];
  const float* tok_Whh_f   = (const float*)d_in[6];
  const float* tok_b_f     = (const float*)d_in[7];
  const float* tok_Wih_b   = (const float*)d_in[8];
  // d_in[9] tok_Whh_b: unused (reverse masked scan at t=clen-1 starts from zero state)
  const float* tok_b_b     = (const float*)d_in[10];
  const float* chk_Wih_f   = (const float*)d_in[11];
  const float* chk_Whh_f   = (const float*)d_in[12];
  const float* chk_b_f     = (const float*)d_in[13];
  const float* chk_Wih_b   = (const float*)d_in[14];
  const float* chk_Whh_b   = (const float*)d_in[15];
  const float* chk_b_b     = (const float*)d_in[16];
  const float* fc_W        = (const float*)d_in[17];
  const float* fc_b        = (const float*)d_in[18];
  float* out = (float*)d_out;

  char* ws = (char*)d_ws;
  size_t off = 0;
  auto alloc = [&](size_t bytes) -> void* {
    void* p = ws + off;
    off += (bytes + 255) & ~(size_t)255;
    return p;
  };
  unsigned short* Wf   = (unsigned short*)alloc((size_t)1024 * 320 * 2);
  unsigned short* Wb   = (unsigned short*)alloc((size_t)1024 * 320 * 2);
  unsigned short* Wcf  = (unsigned short*)alloc((size_t)1024 * 512 * 2);
  unsigned short* Wcb  = (unsigned short*)alloc((size_t)1024 * 512 * 2);
  unsigned short* WhPtok=(unsigned short*)alloc((size_t)512 * 512 * 2);   // frag-major
  unsigned short* WhPcf= (unsigned short*)alloc((size_t)512 * 512 * 2);
  unsigned short* WhPcb= (unsigned short*)alloc((size_t)512 * 512 * 2);
  unsigned short* proj = (unsigned short*)alloc((size_t)30000 * 1024 * 2);
  unsigned short* gxbb = (unsigned short*)alloc((size_t)1024 * 1024 * 2);
  unsigned short* gxcf = (unsigned short*)alloc((size_t)1024 * 1024 * 2);
  unsigned short* gxcb = (unsigned short*)alloc((size_t)1024 * 1024 * 2);
  unsigned short* gxcfp= (unsigned short*)alloc((size_t)1024 * 1024 * 2);
  unsigned short* gxcbp= (unsigned short*)alloc((size_t)1024 * 1024 * 2);
  float*          chunks = (float*)alloc((size_t)1024 * 512 * 4);
  unsigned short* cho  = (unsigned short*)alloc((size_t)1024 * 512 * 2);
  unsigned short* gxs  = (unsigned short*)alloc((size_t)1024 * 64 * 1024 * 2);  // 134 MB
  int* clens = (int*)alloc(1024 * 4);
  int* lastv = (int*)alloc(1024 * 4);
  int* order = (int*)alloc(1024 * 4);
  int* glen  = (int*)alloc(64 * 4);

  // allow >64 KB dynamic LDS for the recurrent kernels (gfx950: 160 KB/CU)
  hipFuncSetAttribute((const void*)tok_fwd,
                      hipFuncAttributeMaxDynamicSharedMemorySize, 148096);
  hipFuncSetAttribute((const void*)chunk_rec,
                      hipFuncAttributeMaxDynamicSharedMemorySize, 147968);

  prep_weights<<<dim3(1024, 4), 256, 0, stream>>>(
      tok_Wih_f, tok_Wih_b, chk_Wih_f, chk_Wih_b, Wf, Wb, Wcf, Wcb);
  prep_whh_frag<<<dim3(512, 3), 256, 0, stream>>>(
      tok_Whh_f, chk_Whh_f, chk_Whh_b, WhPtok, WhPcf, WhPcb);
  prep_small<<<1, 1024, 0, stream>>>(x, x_chunk_len, clens, lastv, order, glen);

  // vocab pre-projection: proj = emb x tok_Wih_f^T
  gemm_bf<<<dim3(4, 235), 256, 0, stream>>>(emb, nullptr, 30000, 300, 300, 320, Wf, proj);
  // backward gx for last tokens only
  gemm_bf<<<dim3(4, 8), 256, 0, stream>>>(emb, lastv, 1024, 300, 300, 320, Wb, gxbb);
  bwd_step<<<1024, 256, 0, stream>>>(gxbb, tok_b_b, chunks);
  // pre-gather forward gate projections (gate-packed, bias folded, t-major/16)
  gather_gx<<<dim3(64, 1024), 256, 0, stream>>>(proj, x, order, clens, glen, tok_b_f, gxs);
  // forward token recurrence: 64 blocks x 16 seqs x 16 waves
  tok_fwd<<<64, 1024, 148096, stream>>>(gxs, WhPtok, order, clens, glen, chunks);
  // chunk-level input projections
  gemm_bf<<<dim3(4, 8), 256, 0, stream>>>(chunks, nullptr, 1024, 512, 512, 512, Wcf, gxcf);
  gemm_bf<<<dim3(4, 8), 256, 0, stream>>>(chunks, nullptr, 1024, 512, 512, 512, Wcb, gxcb);
  repack4<<<dim3(1024, 2), 256, 0, stream>>>(gxcf, gxcb, chk_b_f, chk_b_b, gxcfp, gxcbp);
  // chunk BiLSTM: 4 blocks (2 dir x 2 m-groups) x 16 waves
  chunk_rec<<<4, 1024, 147968, stream>>>(gxcfp, gxcbp, WhPcf, WhPcb, x_len, cho);
  // final FC
  fc_kernel<<<1024, 64, 0, stream>>>(cho, fc_W, fc_b, out);
}